// Round 1
// 953.343 us; speedup vs baseline: 1.0177x; 1.0177x over previous
//
#include <hip/hip_runtime.h>
#include <cstdint>

// ---- problem constants (B=8,T=4096 -> N=32768; EMB=1024; HID=2048; E=8; k=2) ----
#define NTOK   32768
#define EMB_D  1024
#define HID_H  2048
#define NEXP   8
#define CAP    5120               // int(1.25 * 32768 / 8)
#define MROWS  (NEXP * CAP)       // 40960 expert-buffer rows total
#define NCHUNK 32                 // token chunks for parallel scan (1024 tokens each)

typedef __bf16 bf16_t;
typedef bf16_t bf16x8 __attribute__((ext_vector_type(8)));
typedef float  f32x4  __attribute__((ext_vector_type(4)));

typedef __attribute__((address_space(3))) void       lds_void_t;
typedef const __attribute__((address_space(1))) void g_void_t;

__device__ __forceinline__ void gload_lds16(const void* g, void* l) {
    __builtin_amdgcn_global_load_lds((g_void_t*)(uintptr_t)g,
                                     (lds_void_t*)(uint32_t)(uintptr_t)l, 16, 0, 0);
}

// =====================================================================
// Router: logits = x@wr + br ; z-loss partials ; softmax ; top-2
// =====================================================================
__global__ void router_kernel(const float* __restrict__ x, const float* __restrict__ wr,
                              const float* __restrict__ br, int2* __restrict__ top2,
                              float* __restrict__ zsum) {
    __shared__ float s_wr[NEXP * EMB_D];   // [e][d], 32 KB
    __shared__ float s_z[4];
    const int tid = threadIdx.x;           // 256
    for (int i = tid; i < NEXP * EMB_D; i += 256) {
        int d = i >> 3, e = i & 7;         // wr is [d][e] row-major
        s_wr[e * EMB_D + d] = wr[i];
    }
    __syncthreads();
    const int wid = tid >> 6, lane = tid & 63;
    const int t = blockIdx.x * 4 + wid;
    const float* xr = x + (size_t)t * EMB_D;

    float acc[NEXP];
#pragma unroll
    for (int e = 0; e < NEXP; e++) acc[e] = 0.f;
#pragma unroll
    for (int it = 0; it < EMB_D / 64; ++it) {
        float xv = xr[lane + 64 * it];
#pragma unroll
        for (int e = 0; e < NEXP; e++) acc[e] += xv * s_wr[e * EMB_D + lane + 64 * it];
    }
#pragma unroll
    for (int e = 0; e < NEXP; e++) {
        float v = acc[e];
#pragma unroll
        for (int off = 32; off > 0; off >>= 1) v += __shfl_xor(v, off);
        acc[e] = v;
    }
    if (lane == 0) {
        float lg[NEXP]; float zs = 0.f;
#pragma unroll
        for (int e = 0; e < NEXP; e++) { lg[e] = acc[e] + br[e]; zs += lg[e] * lg[e]; }
        s_z[wid] = zs;
        float mx = lg[0];
        for (int e = 1; e < NEXP; e++) mx = fmaxf(mx, lg[e]);
        float p[NEXP]; float se = 0.f;
        for (int e = 0; e < NEXP; e++) { p[e] = expf(lg[e] - mx); se += p[e]; }
        for (int e = 0; e < NEXP; e++) p[e] = p[e] / se;
        int i0 = 0; float b0 = p[0];
        for (int e = 1; e < NEXP; e++) if (p[e] > b0) { b0 = p[e]; i0 = e; }
        int i1 = -1; float b1v = -1.f;
        for (int e = 0; e < NEXP; e++) if (e != i0 && p[e] > b1v) { b1v = p[e]; i1 = e; }
        top2[t] = make_int2(i0, i1);
    }
    __syncthreads();
    if (tid == 0) unsafeAtomicAdd(zsum, s_z[0] + s_z[1] + s_z[2] + s_z[3]);
}

// =====================================================================
// Parallel capacity scan: count -> prefix -> place (+inverse map) -> pad
// =====================================================================
__global__ void count_kernel(const int2* __restrict__ top2, int* __restrict__ counts) {
    const int chunk = blockIdx.x;          // 32 chunks x 1024 tokens
    const int tid = threadIdx.x;           // 1024
    const int wid = tid >> 6, lane = tid & 63;
    __shared__ int wcnt[NEXP][16];
    const int2 tp = top2[chunk * 1024 + tid];
#pragma unroll
    for (int e = 0; e < NEXP; e++) {
        const bool m = (tp.x == e) || (tp.y == e);
        unsigned long long bal = __ballot(m);
        if (lane == 0) wcnt[e][wid] = __popcll(bal);
    }
    __syncthreads();
    if (tid < NEXP) {
        int s = 0;
        for (int w = 0; w < 16; w++) s += wcnt[tid][w];
        counts[chunk * NEXP + tid] = s;
    }
}

__global__ void prefix_kernel(const int* __restrict__ counts, int* __restrict__ base,
                              int* __restrict__ usage) {
    const int e = threadIdx.x;
    if (e < NEXP) {
        int run = 0;
        for (int c = 0; c < NCHUNK; c++) {
            base[c * NEXP + e] = run;
            run += counts[c * NEXP + e];
        }
        usage[e] = run < CAP ? run : CAP;
    }
}

__global__ void place_kernel(const int2* __restrict__ top2, const int* __restrict__ base,
                             int* __restrict__ buf, int* __restrict__ inv) {
    const int chunk = blockIdx.x;
    const int tid = threadIdx.x;           // 1024
    const int wid = tid >> 6, lane = tid & 63;
    const int t = chunk * 1024 + tid;
    __shared__ int wpre[NEXP][16];
    const int2 tp = top2[t];
    int lpre[NEXP]; bool mm[NEXP];
#pragma unroll
    for (int e = 0; e < NEXP; e++) {
        mm[e] = (tp.x == e) || (tp.y == e);
        unsigned long long bal = __ballot(mm[e]);
        lpre[e] = __popcll(bal & ((1ull << lane) - 1ull));
        if (lane == 0) wpre[e][wid] = __popcll(bal);
    }
    __syncthreads();
    if (tid < NEXP) {
        int a = 0;
        for (int w = 0; w < 16; w++) { int v = wpre[tid][w]; wpre[tid][w] = a; a += v; }
    }
    __syncthreads();
#pragma unroll
    for (int e = 0; e < NEXP; e++) {
        if (mm[e]) {
            const int pos = base[chunk * NEXP + e] + wpre[e][wid] + lpre[e];
            const int slot = (tp.x == e) ? 0 : 1;
            if (pos < CAP) {
                const int row = e * CAP + pos;
                buf[row] = t;
                inv[t * 2 + slot] = row;
            } else {
                inv[t * 2 + slot] = -1;
            }
        }
    }
}

__global__ void pad_kernel(const int* __restrict__ usage, int* __restrict__ buf) {
    const int e = blockIdx.x;
    const int u = usage[e];
    for (int p = u + threadIdx.x; p < CAP; p += blockDim.x) buf[e * CAP + p] = NTOK;
}

// =====================================================================
// Gather: Xg[row][d] = bf16(x[buf[row]][d])  (zero row for pad)
// =====================================================================
__global__ void gather_kernel(const float* __restrict__ x, const int* __restrict__ buf,
                              bf16_t* __restrict__ Xg) {
    const int row = blockIdx.x;
    const int t = buf[row];
    const int tid = threadIdx.x;   // 128, 8 elems each
    bf16x8 v;
    if (t >= 0 && t < NTOK) {
        const float* xr = x + (size_t)t * EMB_D + tid * 8;
        const float4 a = *(const float4*)(xr);
        const float4 b = *(const float4*)(xr + 4);
        v[0] = (bf16_t)a.x; v[1] = (bf16_t)a.y; v[2] = (bf16_t)a.z; v[3] = (bf16_t)a.w;
        v[4] = (bf16_t)b.x; v[5] = (bf16_t)b.y; v[6] = (bf16_t)b.z; v[7] = (bf16_t)b.w;
    } else {
#pragma unroll
        for (int i = 0; i < 8; i++) v[i] = (bf16_t)0.f;
    }
    *(bf16x8*)(Xg + (size_t)row * EMB_D + tid * 8) = v;
}

// =====================================================================
// Transpose + convert: in[e][R][C] fp32 -> out[e][C][R] bf16
// =====================================================================
__global__ void transpose_conv_kernel(const float* __restrict__ in, bf16_t* __restrict__ out,
                                      int R, int C) {
    __shared__ bf16_t tile[64][72];
    const int e = blockIdx.z;
    const int c0 = blockIdx.x * 64, r0 = blockIdx.y * 64;
    const float*  ip = in  + (size_t)e * R * C;
    bf16_t*       op = out + (size_t)e * R * C;
    const int tid = threadIdx.x;   // 256
    const int tr = tid >> 4;
    const int tc = (tid & 15) * 4;
#pragma unroll
    for (int rr = 0; rr < 64; rr += 16) {
        const float4 v = *(const float4*)(ip + (size_t)(r0 + tr + rr) * C + (c0 + tc));
        tile[tr + rr][tc + 0] = (bf16_t)v.x;
        tile[tr + rr][tc + 1] = (bf16_t)v.y;
        tile[tr + rr][tc + 2] = (bf16_t)v.z;
        tile[tr + rr][tc + 3] = (bf16_t)v.w;
    }
    __syncthreads();
    const int oc = tid >> 2;
    const int og = (tid & 3) * 16;
    bf16x8 v0, v1;
#pragma unroll
    for (int i = 0; i < 8; i++) v0[i] = tile[og + i][oc];
#pragma unroll
    for (int i = 0; i < 8; i++) v1[i] = tile[og + 8 + i][oc];
    *(bf16x8*)(op + (size_t)(c0 + oc) * R + r0 + og)     = v0;
    *(bf16x8*)(op + (size_t)(c0 + oc) * R + r0 + og + 8) = v1;
}

// =====================================================================
// 256x256 8-phase MFMA GEMM (T2 st_16x32 swizzle + T3/T4 counted vmcnt + T5)
//   BM=BN=256, BK=64, 512 threads = 8 waves (2 M x 4 N), per-wave 128x64 out.
//   LDS: 2 buffers x (A 32KB + B 32KB) = 128 KB (dynamic).
//   Staging: half-tiles of 128 rows x 64 K (16KB), order [B0,B1,A0,A1],
//   lead 6 half-tiles; s_waitcnt vmcnt(4) once per K-tile (2 half-tiles in
//   flight across barriers -> never drained to 0 in the loop).
// =====================================================================
#define BUF_BYTES 65536
#define LDS_TOTAL 131072

__device__ __forceinline__ const bf16x8* fragp(const char* base, int row, int ks, int quad) {
    int b = row * 128 + ks * 64 + quad * 16;
    b ^= ((b >> 9) & 1) << 5;              // st_16x32 XOR swizzle (read side)
    return (const bf16x8*)(base + b);
}

// stage one half-tile: idx = 4*ktile + part, part order [B0,B1,A0,A1].
// LDS dest linear (global_load_lds requirement); global src inverse-swizzled.
__device__ __forceinline__ void stage_ht(const bf16_t* __restrict__ Ap,
                                         const bf16_t* __restrict__ Bp,
                                         int K, int NT, char* lds0, int idx,
                                         size_t off0, int tid) {
    if (idx >= 4 * NT) return;
    const int t = idx >> 2, part = idx & 3;
    char* dst = lds0 + (t & 1) * BUF_BYTES + ((part < 2) ? 32768 : 0)
              + (part & 1) * 16384 + tid * 16;
    const bf16_t* src = ((part < 2) ? Bp : Ap)
                      + (size_t)((part & 1) * 128) * K + (size_t)t * 64 + off0;
    gload_lds16(src, dst);                       // rows 0-63 of half-tile
    gload_lds16(src + (size_t)64 * K, dst + 8192);   // rows 64-127
}

template <int NT>
__device__ __forceinline__ void mainloop256(const bf16_t* __restrict__ Ap,
                                            const bf16_t* __restrict__ Bp,
                                            char* lds0, f32x4 (&acc)[8][4]) {
    const int K = NT * 64;
    const int tid = threadIdx.x;
    const int lane = tid & 63, wid = tid >> 6;
    const int wm = wid >> 2, wn = wid & 3;
    const int quad = lane >> 4, l16 = lane & 15;

    // pre-swizzled global source offset for this thread's linear LDS chunk
    const int o0 = tid * 16;
    const int lg = o0 ^ (((o0 >> 9) & 1) << 5);
    const size_t off0 = (size_t)(lg >> 7) * K + ((lg & 127) >> 1);

    // prologue: tile0 fully + B halves of tile1 (6 half-tiles)
#pragma unroll
    for (int idx = 0; idx < 6; ++idx) stage_ht(Ap, Bp, K, NT, lds0, idx, off0, tid);
    asm volatile("s_waitcnt vmcnt(4)");          // tile0 resident
    __builtin_amdgcn_s_barrier();

    bf16x8 a[8], bl[4], bh[4];
    for (int t = 0; t < NT; ++t) {
        const char* bufA = lds0 + (t & 1) * BUF_BYTES;
        const char* bufB = bufA + 32768;
        const int pbase = 4 * t + 6;

        // ---- P0: read A(mf0-3)+B(nf0-1) [12 rds]; stage A0(t+1); Q(m-lo,n-lo)
#pragma unroll
        for (int mf = 0; mf < 4; ++mf)
#pragma unroll
            for (int ks = 0; ks < 2; ++ks)
                a[mf * 2 + ks] = *fragp(bufA, wm * 128 + mf * 16 + l16, ks, quad);
#pragma unroll
        for (int nf = 0; nf < 2; ++nf)
#pragma unroll
            for (int ks = 0; ks < 2; ++ks)
                bl[nf * 2 + ks] = *fragp(bufB, wn * 64 + nf * 16 + l16, ks, quad);
        stage_ht(Ap, Bp, K, NT, lds0, pbase + 0, off0, tid);
        __builtin_amdgcn_s_barrier();
        asm volatile("s_waitcnt lgkmcnt(0)");
        __builtin_amdgcn_s_setprio(1);
#pragma unroll
        for (int mf = 0; mf < 4; ++mf)
#pragma unroll
            for (int nf = 0; nf < 2; ++nf)
#pragma unroll
                for (int ks = 0; ks < 2; ++ks)
                    acc[mf][nf] = __builtin_amdgcn_mfma_f32_16x16x32_bf16(
                        a[mf * 2 + ks], bl[nf * 2 + ks], acc[mf][nf], 0, 0, 0);
        __builtin_amdgcn_s_setprio(0);
        __builtin_amdgcn_s_barrier();

        // ---- P1: read B(nf2-3) [4 rds]; stage A1(t+1); Q(m-lo,n-hi)
#pragma unroll
        for (int nf = 0; nf < 2; ++nf)
#pragma unroll
            for (int ks = 0; ks < 2; ++ks)
                bh[nf * 2 + ks] = *fragp(bufB, wn * 64 + (nf + 2) * 16 + l16, ks, quad);
        stage_ht(Ap, Bp, K, NT, lds0, pbase + 1, off0, tid);
        __builtin_amdgcn_s_barrier();
        asm volatile("s_waitcnt lgkmcnt(0)");
        __builtin_amdgcn_s_setprio(1);
#pragma unroll
        for (int mf = 0; mf < 4; ++mf)
#pragma unroll
            for (int nf = 0; nf < 2; ++nf)
#pragma unroll
                for (int ks = 0; ks < 2; ++ks)
                    acc[mf][nf + 2] = __builtin_amdgcn_mfma_f32_16x16x32_bf16(
                        a[mf * 2 + ks], bh[nf * 2 + ks], acc[mf][nf + 2], 0, 0, 0);
        __builtin_amdgcn_s_setprio(0);
        __builtin_amdgcn_s_barrier();

        // ---- P2: read A(mf4-7) [8 rds]; stage B0(t+2); Q(m-hi,n-hi)
#pragma unroll
        for (int mf = 0; mf < 4; ++mf)
#pragma unroll
            for (int ks = 0; ks < 2; ++ks)
                a[mf * 2 + ks] = *fragp(bufA, wm * 128 + (mf + 4) * 16 + l16, ks, quad);
        stage_ht(Ap, Bp, K, NT, lds0, pbase + 2, off0, tid);
        __builtin_amdgcn_s_barrier();
        asm volatile("s_waitcnt lgkmcnt(0)");
        __builtin_amdgcn_s_setprio(1);
#pragma unroll
        for (int mf = 0; mf < 4; ++mf)
#pragma unroll
            for (int nf = 0; nf < 2; ++nf)
#pragma unroll
                for (int ks = 0; ks < 2; ++ks)
                    acc[mf + 4][nf + 2] = __builtin_amdgcn_mfma_f32_16x16x32_bf16(
                        a[mf * 2 + ks], bh[nf * 2 + ks], acc[mf + 4][nf + 2], 0, 0, 0);
        __builtin_amdgcn_s_setprio(0);
        __builtin_amdgcn_s_barrier();

        // ---- P3: no reads; stage B1(t+2); Q(m-hi,n-lo); counted vmcnt
        stage_ht(Ap, Bp, K, NT, lds0, pbase + 3, off0, tid);
        __builtin_amdgcn_s_setprio(1);
#pragma unroll
        for (int mf = 0; mf < 4; ++mf)
#pragma unroll
            for (int nf = 0; nf < 2; ++nf)
#pragma unroll
                for (int ks = 0; ks < 2; ++ks)
                    acc[mf + 4][nf] = __builtin_amdgcn_mfma_f32_16x16x32_bf16(
                        a[mf * 2 + ks], bl[nf * 2 + ks], acc[mf + 4][nf], 0, 0, 0);
        __builtin_amdgcn_s_setprio(0);
        asm volatile("s_waitcnt vmcnt(4)");      // tile t+1 resident; 2 half-tiles in flight
        __builtin_amdgcn_s_barrier();
    }
}

// GEMM1: H = gelu_exact(Xg @ w1t^T + b1), bf16 out.
__global__ __launch_bounds__(512, 2) void gemm1_kernel(const bf16_t* __restrict__ Xg,
                                                       const bf16_t* __restrict__ w1t,
                                                       const float* __restrict__ b1,
                                                       bf16_t* __restrict__ H) {
    extern __shared__ char lds0[];
    const int bn = blockIdx.x, bm = blockIdx.y;
    const int e = bm / (CAP / 256);
    const bf16_t* Ap = Xg + (size_t)bm * 256 * EMB_D;
    const bf16_t* Bp = w1t + ((size_t)e * HID_H + bn * 256) * EMB_D;
    f32x4 acc[8][4];
    const f32x4 z4 = {0.f, 0.f, 0.f, 0.f};
#pragma unroll
    for (int i = 0; i < 8; i++)
#pragma unroll
        for (int j = 0; j < 4; j++) acc[i][j] = z4;

    mainloop256<EMB_D / 64>(Ap, Bp, lds0, acc);

    const int tid = threadIdx.x;
    const int lane = tid & 63, wid = tid >> 6;
    const int wm = wid >> 2, wn = wid & 3;
    const int quad = lane >> 4, l16 = lane & 15;
#pragma unroll
    for (int nf = 0; nf < 4; ++nf) {
        const int col = bn * 256 + wn * 64 + nf * 16 + l16;
        const float bias = b1[e * HID_H + col];
#pragma unroll
        for (int mf = 0; mf < 8; ++mf) {
            const int row = bm * 256 + wm * 128 + mf * 16 + quad * 4;
#pragma unroll
            for (int r = 0; r < 4; ++r) {
                const float v = acc[mf][nf][r] + bias;
                const float g = 0.5f * v * (1.f + erff(v * 0.7071067811865475f));
                H[(size_t)(row + r) * HID_H + col] = (bf16_t)g;
            }
        }
    }
}

// GEMM2: Yg = H @ w2t^T (bf16, dense; bias added in combine).
__global__ __launch_bounds__(512, 2) void gemm2_kernel(const bf16_t* __restrict__ H,
                                                       const bf16_t* __restrict__ w2t,
                                                       bf16_t* __restrict__ Yg) {
    extern __shared__ char lds0[];
    const int bn = blockIdx.x, bm = blockIdx.y;
    const int e = bm / (CAP / 256);
    const bf16_t* Ap = H + (size_t)bm * 256 * HID_H;
    const bf16_t* Bp = w2t + ((size_t)e * EMB_D + bn * 256) * HID_H;
    f32x4 acc[8][4];
    const f32x4 z4 = {0.f, 0.f, 0.f, 0.f};
#pragma unroll
    for (int i = 0; i < 8; i++)
#pragma unroll
        for (int j = 0; j < 4; j++) acc[i][j] = z4;

    mainloop256<HID_H / 64>(Ap, Bp, lds0, acc);

    const int tid = threadIdx.x;
    const int lane = tid & 63, wid = tid >> 6;
    const int wm = wid >> 2, wn = wid & 3;
    const int quad = lane >> 4, l16 = lane & 15;
#pragma unroll
    for (int nf = 0; nf < 4; ++nf) {
        const int col = bn * 256 + wn * 64 + nf * 16 + l16;
#pragma unroll
        for (int mf = 0; mf < 8; ++mf) {
            const int row = bm * 256 + wm * 128 + mf * 16 + quad * 4;
#pragma unroll
            for (int r = 0; r < 4; ++r)
                Yg[(size_t)(row + r) * EMB_D + col] = (bf16_t)acc[mf][nf][r];
        }
    }
}

// =====================================================================
// Combine: out[t] = sum over kept slots (Yg[row] + b2[expert]) ; 0 if dropped
// =====================================================================
__global__ void combine_kernel(const bf16_t* __restrict__ Yg, const float* __restrict__ b2,
                               const int* __restrict__ inv, float* __restrict__ out) {
    const int t = blockIdx.x;
    const int tid = threadIdx.x;   // 128, 8 floats each
    const int d = tid * 8;
    const int r0 = inv[t * 2], r1 = inv[t * 2 + 1];
    float acc[8];
#pragma unroll
    for (int i = 0; i < 8; i++) acc[i] = 0.f;
    if (r0 >= 0) {
        const int e = r0 / CAP;
        const bf16x8 v = *(const bf16x8*)(Yg + (size_t)r0 * EMB_D + d);
        const float* bp = b2 + e * EMB_D + d;
#pragma unroll
        for (int i = 0; i < 8; i++) acc[i] += (float)v[i] + bp[i];
    }
    if (r1 >= 0) {
        const int e = r1 / CAP;
        const bf16x8 v = *(const bf16x8*)(Yg + (size_t)r1 * EMB_D + d);
        const float* bp = b2 + e * EMB_D + d;
#pragma unroll
        for (int i = 0; i < 8; i++) acc[i] += (float)v[i] + bp[i];
    }
    float4 o0 = {acc[0], acc[1], acc[2], acc[3]};
    float4 o1 = {acc[4], acc[5], acc[6], acc[7]};
    *(float4*)(out + (size_t)t * EMB_D + d)     = o0;
    *(float4*)(out + (size_t)t * EMB_D + d + 4) = o1;
}

// =====================================================================
// Finalize: loss = E*sum(load^2) + 0.001*mean(logits^2); usage floats.
// =====================================================================
__global__ void finalize_kernel(const int* __restrict__ usage, const float* __restrict__ zsum,
                                float* __restrict__ out) {
    if (threadIdx.x == 0) {
        float u[NEXP], s = 0.f;
        for (int e = 0; e < NEXP; e++) { u[e] = (float)usage[e]; s += u[e]; }
        const float inv = 1.f / (s + 1e-6f);
        float bal = 0.f;
        for (int e = 0; e < NEXP; e++) { const float l = u[e] * inv; bal += l * l; }
        bal *= (float)NEXP;
        const float z = 0.001f * zsum[0] / (float)((size_t)NTOK * NEXP);
        out[(size_t)NTOK * EMB_D] = bal + z;
        for (int e = 0; e < NEXP; e++) out[(size_t)NTOK * EMB_D + 1 + e] = u[e];
    }
}

extern "C" void kernel_launch(void* const* d_in, const int* in_sizes, int n_in,
                              void* d_out, int out_size, void* d_ws, size_t ws_size,
                              hipStream_t stream) {
    (void)in_sizes; (void)n_in; (void)out_size;
    const float* x  = (const float*)d_in[0];
    const float* wr = (const float*)d_in[1];
    const float* br = (const float*)d_in[2];
    const float* w1 = (const float*)d_in[3];
    const float* b1 = (const float*)d_in[4];
    const float* w2 = (const float*)d_in[5];
    const float* b2 = (const float*)d_in[6];
    float* out = (float*)d_out;

    uint8_t* ws = (uint8_t*)d_ws;
    size_t off = 0;
    auto carve = [&](size_t bytes) -> void* {
        off = (off + 255) & ~(size_t)255;
        void* p = ws + off;
        off += bytes;
        return p;
    };
    float*  zsum  = (float*)carve(sizeof(float));
    int*    usage = (int*)carve(NEXP * sizeof(int));
    int*    counts = (int*)carve((size_t)NCHUNK * NEXP * sizeof(int));
    int*    base   = (int*)carve((size_t)NCHUNK * NEXP * sizeof(int));
    int2*   top2 = (int2*)carve((size_t)NTOK * sizeof(int2));
    int*    buf  = (int*)carve((size_t)MROWS * sizeof(int));
    int*    inv  = (int*)carve((size_t)NTOK * 2 * sizeof(int));
    bf16_t* Xg   = (bf16_t*)carve((size_t)MROWS * EMB_D * sizeof(bf16_t));
    bf16_t* w1t  = (bf16_t*)carve((size_t)NEXP * HID_H * EMB_D * sizeof(bf16_t));
    bf16_t* w2t  = (bf16_t*)carve((size_t)NEXP * EMB_D * HID_H * sizeof(bf16_t));
    bf16_t* H    = (bf16_t*)carve((size_t)MROWS * HID_H * sizeof(bf16_t));
    bf16_t* Yg   = Xg;   // Xg is dead after gemm1 -> reuse for gemm2 output
    if (off > ws_size) return;   // workspace too small: fail loudly

    static bool attr_set = false;
    if (!attr_set) {
        hipFuncSetAttribute(reinterpret_cast<const void*>(&gemm1_kernel),
                            hipFuncAttributeMaxDynamicSharedMemorySize, LDS_TOTAL);
        hipFuncSetAttribute(reinterpret_cast<const void*>(&gemm2_kernel),
                            hipFuncAttributeMaxDynamicSharedMemorySize, LDS_TOTAL);
        attr_set = true;
    }

    hipMemsetAsync(zsum, 0, sizeof(float), stream);

    router_kernel<<<NTOK / 4, 256, 0, stream>>>(x, wr, br, top2, zsum);
    count_kernel<<<NCHUNK, 1024, 0, stream>>>(top2, counts);
    prefix_kernel<<<1, 64, 0, stream>>>(counts, base, usage);
    place_kernel<<<NCHUNK, 1024, 0, stream>>>(top2, base, buf, inv);
    pad_kernel<<<NEXP, 256, 0, stream>>>(usage, buf);
    gather_kernel<<<MROWS, 128, 0, stream>>>(x, buf, Xg);
    transpose_conv_kernel<<<dim3(HID_H / 64, EMB_D / 64, NEXP), 256, 0, stream>>>(w1, w1t, EMB_D, HID_H);
    transpose_conv_kernel<<<dim3(EMB_D / 64, HID_H / 64, NEXP), 256, 0, stream>>>(w2, w2t, HID_H, EMB_D);
    gemm1_kernel<<<dim3(HID_H / 256, MROWS / 256), 512, LDS_TOTAL, stream>>>(Xg, w1t, b1, H);
    gemm2_kernel<<<dim3(EMB_D / 256, MROWS / 256), 512, LDS_TOTAL, stream>>>(H, w2t, Yg);
    combine_kernel<<<NTOK, 128, 0, stream>>>(Yg, b2, inv, out);
    finalize_kernel<<<1, 64, 0, stream>>>(usage, zsum, out);
}

// Round 2
// 932.491 us; speedup vs baseline: 1.0405x; 1.0224x over previous
//
#include <hip/hip_runtime.h>
#include <cstdint>

// ---- problem constants (B=8,T=4096 -> N=32768; EMB=1024; HID=2048; E=8; k=2) ----
#define NTOK   32768
#define EMB_D  1024
#define HID_H  2048
#define NEXP   8
#define CAP    5120               // int(1.25 * 32768 / 8)
#define MROWS  (NEXP * CAP)       // 40960 expert-buffer rows total
#define NCHUNK 32                 // token chunks for parallel scan (1024 tokens each)

typedef __bf16 bf16_t;
typedef bf16_t bf16x8 __attribute__((ext_vector_type(8)));
typedef float  f32x4  __attribute__((ext_vector_type(4)));

typedef __attribute__((address_space(3))) void       lds_void_t;
typedef const __attribute__((address_space(1))) void g_void_t;

__device__ __forceinline__ void gload_lds16(const void* g, void* l) {
    __builtin_amdgcn_global_load_lds((g_void_t*)(uintptr_t)g,
                                     (lds_void_t*)(uint32_t)(uintptr_t)l, 16, 0, 0);
}

// =====================================================================
// Router: logits = x@wr + br ; z-loss partials ; softmax ; top-2
// =====================================================================
__global__ void router_kernel(const float* __restrict__ x, const float* __restrict__ wr,
                              const float* __restrict__ br, int2* __restrict__ top2,
                              float* __restrict__ zsum) {
    __shared__ float s_wr[NEXP * EMB_D];   // [e][d], 32 KB
    __shared__ float s_z[4];
    const int tid = threadIdx.x;           // 256
    for (int i = tid; i < NEXP * EMB_D; i += 256) {
        int d = i >> 3, e = i & 7;         // wr is [d][e] row-major
        s_wr[e * EMB_D + d] = wr[i];
    }
    __syncthreads();
    const int wid = tid >> 6, lane = tid & 63;
    const int t = blockIdx.x * 4 + wid;
    const float* xr = x + (size_t)t * EMB_D;

    float acc[NEXP];
#pragma unroll
    for (int e = 0; e < NEXP; e++) acc[e] = 0.f;
#pragma unroll
    for (int it = 0; it < EMB_D / 64; ++it) {
        float xv = xr[lane + 64 * it];
#pragma unroll
        for (int e = 0; e < NEXP; e++) acc[e] += xv * s_wr[e * EMB_D + lane + 64 * it];
    }
#pragma unroll
    for (int e = 0; e < NEXP; e++) {
        float v = acc[e];
#pragma unroll
        for (int off = 32; off > 0; off >>= 1) v += __shfl_xor(v, off);
        acc[e] = v;
    }
    if (lane == 0) {
        float lg[NEXP]; float zs = 0.f;
#pragma unroll
        for (int e = 0; e < NEXP; e++) { lg[e] = acc[e] + br[e]; zs += lg[e] * lg[e]; }
        s_z[wid] = zs;
        float mx = lg[0];
        for (int e = 1; e < NEXP; e++) mx = fmaxf(mx, lg[e]);
        float p[NEXP]; float se = 0.f;
        for (int e = 0; e < NEXP; e++) { p[e] = expf(lg[e] - mx); se += p[e]; }
        for (int e = 0; e < NEXP; e++) p[e] = p[e] / se;
        int i0 = 0; float b0 = p[0];
        for (int e = 1; e < NEXP; e++) if (p[e] > b0) { b0 = p[e]; i0 = e; }
        int i1 = -1; float b1v = -1.f;
        for (int e = 0; e < NEXP; e++) if (e != i0 && p[e] > b1v) { b1v = p[e]; i1 = e; }
        top2[t] = make_int2(i0, i1);
    }
    __syncthreads();
    if (tid == 0) unsafeAtomicAdd(zsum, s_z[0] + s_z[1] + s_z[2] + s_z[3]);
}

// =====================================================================
// Parallel capacity scan: count -> prefix -> place (+inverse map) -> pad
// =====================================================================
__global__ void count_kernel(const int2* __restrict__ top2, int* __restrict__ counts) {
    const int chunk = blockIdx.x;          // 32 chunks x 1024 tokens
    const int tid = threadIdx.x;           // 1024
    const int wid = tid >> 6, lane = tid & 63;
    __shared__ int wcnt[NEXP][16];
    const int2 tp = top2[chunk * 1024 + tid];
#pragma unroll
    for (int e = 0; e < NEXP; e++) {
        const bool m = (tp.x == e) || (tp.y == e);
        unsigned long long bal = __ballot(m);
        if (lane == 0) wcnt[e][wid] = __popcll(bal);
    }
    __syncthreads();
    if (tid < NEXP) {
        int s = 0;
        for (int w = 0; w < 16; w++) s += wcnt[tid][w];
        counts[chunk * NEXP + tid] = s;
    }
}

__global__ void prefix_kernel(const int* __restrict__ counts, int* __restrict__ base,
                              int* __restrict__ usage) {
    const int e = threadIdx.x;
    if (e < NEXP) {
        int run = 0;
        for (int c = 0; c < NCHUNK; c++) {
            base[c * NEXP + e] = run;
            run += counts[c * NEXP + e];
        }
        usage[e] = run < CAP ? run : CAP;
    }
}

__global__ void place_kernel(const int2* __restrict__ top2, const int* __restrict__ base,
                             int* __restrict__ buf, int* __restrict__ inv) {
    const int chunk = blockIdx.x;
    const int tid = threadIdx.x;           // 1024
    const int wid = tid >> 6, lane = tid & 63;
    const int t = chunk * 1024 + tid;
    __shared__ int wpre[NEXP][16];
    const int2 tp = top2[t];
    int lpre[NEXP]; bool mm[NEXP];
#pragma unroll
    for (int e = 0; e < NEXP; e++) {
        mm[e] = (tp.x == e) || (tp.y == e);
        unsigned long long bal = __ballot(mm[e]);
        lpre[e] = __popcll(bal & ((1ull << lane) - 1ull));
        if (lane == 0) wpre[e][wid] = __popcll(bal);
    }
    __syncthreads();
    if (tid < NEXP) {
        int a = 0;
        for (int w = 0; w < 16; w++) { int v = wpre[tid][w]; wpre[tid][w] = a; a += v; }
    }
    __syncthreads();
#pragma unroll
    for (int e = 0; e < NEXP; e++) {
        if (mm[e]) {
            const int pos = base[chunk * NEXP + e] + wpre[e][wid] + lpre[e];
            const int slot = (tp.x == e) ? 0 : 1;
            if (pos < CAP) {
                const int row = e * CAP + pos;
                buf[row] = t;
                inv[t * 2 + slot] = row;
            } else {
                inv[t * 2 + slot] = -1;
            }
        }
    }
}

__global__ void pad_kernel(const int* __restrict__ usage, int* __restrict__ buf) {
    const int e = blockIdx.x;
    const int u = usage[e];
    for (int p = u + threadIdx.x; p < CAP; p += blockDim.x) buf[e * CAP + p] = NTOK;
}

// =====================================================================
// Gather: Xg[row][d] = bf16(x[buf[row]][d])  (zero row for pad)
// =====================================================================
__global__ void gather_kernel(const float* __restrict__ x, const int* __restrict__ buf,
                              bf16_t* __restrict__ Xg) {
    const int row = blockIdx.x;
    const int t = buf[row];
    const int tid = threadIdx.x;   // 128, 8 elems each
    bf16x8 v;
    if (t >= 0 && t < NTOK) {
        const float* xr = x + (size_t)t * EMB_D + tid * 8;
        const float4 a = *(const float4*)(xr);
        const float4 b = *(const float4*)(xr + 4);
        v[0] = (bf16_t)a.x; v[1] = (bf16_t)a.y; v[2] = (bf16_t)a.z; v[3] = (bf16_t)a.w;
        v[4] = (bf16_t)b.x; v[5] = (bf16_t)b.y; v[6] = (bf16_t)b.z; v[7] = (bf16_t)b.w;
    } else {
#pragma unroll
        for (int i = 0; i < 8; i++) v[i] = (bf16_t)0.f;
    }
    *(bf16x8*)(Xg + (size_t)row * EMB_D + tid * 8) = v;
}

// =====================================================================
// Transpose + convert: in[e][R][C] fp32 -> out[e][C][R] bf16
// =====================================================================
__global__ void transpose_conv_kernel(const float* __restrict__ in, bf16_t* __restrict__ out,
                                      int R, int C) {
    __shared__ bf16_t tile[64][72];
    const int e = blockIdx.z;
    const int c0 = blockIdx.x * 64, r0 = blockIdx.y * 64;
    const float*  ip = in  + (size_t)e * R * C;
    bf16_t*       op = out + (size_t)e * R * C;
    const int tid = threadIdx.x;   // 256
    const int tr = tid >> 4;
    const int tc = (tid & 15) * 4;
#pragma unroll
    for (int rr = 0; rr < 64; rr += 16) {
        const float4 v = *(const float4*)(ip + (size_t)(r0 + tr + rr) * C + (c0 + tc));
        tile[tr + rr][tc + 0] = (bf16_t)v.x;
        tile[tr + rr][tc + 1] = (bf16_t)v.y;
        tile[tr + rr][tc + 2] = (bf16_t)v.z;
        tile[tr + rr][tc + 3] = (bf16_t)v.w;
    }
    __syncthreads();
    const int oc = tid >> 2;
    const int og = (tid & 3) * 16;
    bf16x8 v0, v1;
#pragma unroll
    for (int i = 0; i < 8; i++) v0[i] = tile[og + i][oc];
#pragma unroll
    for (int i = 0; i < 8; i++) v1[i] = tile[og + 8 + i][oc];
    *(bf16x8*)(op + (size_t)(c0 + oc) * R + r0 + og)     = v0;
    *(bf16x8*)(op + (size_t)(c0 + oc) * R + r0 + og + 8) = v1;
}

// =====================================================================
// 256x256 8-phase MFMA GEMM, split-K-plane LDS layout (conflict-free)
//   BM=BN=256, BK=64, 512 threads = 8 waves (2 M x 4 N), per-wave 128x64 out.
//   LDS: 2 buffers x (A 32KB + B 32KB) = 128 KB (dynamic).
//   Each 32KB matrix segment = 2 planes: plane[ks][row][32 k-elems] (row
//   stride 64 B). A fragment read (16 rows x quad*16B within a 64B row) is a
//   contiguous 1024B block -> ZERO bank conflicts, no swizzle on either side.
//   Staging: 4 units/tile of 16KB, order [Bks0,Bks1,Aks0,Aks1], lead 6 units;
//   s_waitcnt vmcnt(4) once per K-tile (2 units in flight across barriers).
// =====================================================================
#define BUF_BYTES 65536
#define LDS_TOTAL 131072

__device__ __forceinline__ const bf16x8* fragp(const char* base, int row, int ks, int quad) {
    return (const bf16x8*)(base + ks * 16384 + row * 64 + quad * 16);
}

// stage one 16KB unit: idx = 4*ktile + part, part order [Bks0,Bks1,Aks0,Aks1].
// LDS dest linear (global_load_lds requirement); source remapped to split-K.
__device__ __forceinline__ void stage_ht(const bf16_t* __restrict__ Ap,
                                         const bf16_t* __restrict__ Bp,
                                         int K, int NT, char* lds0, int idx, int tid) {
    if (idx >= 4 * NT) return;
    const int t = idx >> 2, part = idx & 3;
    const int ks = part & 1;
    char* dst = lds0 + (t & 1) * BUF_BYTES + ((part < 2) ? 32768 : 0)
              + ks * 16384 + tid * 16;
    const int row0 = tid >> 2;                    // 0..127
    const int kk   = (tid & 3) * 8;               // 0..24 elems within plane row
    const bf16_t* src = ((part < 2) ? Bp : Ap)
                      + (size_t)row0 * K + (size_t)t * 64 + ks * 32 + kk;
    gload_lds16(src, dst);                          // rows 0..127
    gload_lds16(src + (size_t)128 * K, dst + 8192); // rows 128..255
}

template <int NT>
__device__ __forceinline__ void mainloop256(const bf16_t* __restrict__ Ap,
                                            const bf16_t* __restrict__ Bp,
                                            char* lds0, f32x4 (&acc)[8][4]) {
    const int K = NT * 64;
    const int tid = threadIdx.x;
    const int lane = tid & 63, wid = tid >> 6;
    const int wm = wid >> 2, wn = wid & 3;
    const int quad = lane >> 4, l16 = lane & 15;

    // prologue: tile0 fully + B planes of tile1 (6 units)
#pragma unroll
    for (int idx = 0; idx < 6; ++idx) stage_ht(Ap, Bp, K, NT, lds0, idx, tid);
    asm volatile("s_waitcnt vmcnt(4)");          // tile0 resident
    __builtin_amdgcn_s_barrier();

    bf16x8 a[8], bl[4], bh[4];
    for (int t = 0; t < NT; ++t) {
        const char* bufA = lds0 + (t & 1) * BUF_BYTES;
        const char* bufB = bufA + 32768;
        const int pbase = 4 * t + 6;

        // ---- P0: read A(mf0-3)+B(nf0-1) [12 rds]; stage Aks0(t+1); Q(m-lo,n-lo)
#pragma unroll
        for (int mf = 0; mf < 4; ++mf)
#pragma unroll
            for (int ks = 0; ks < 2; ++ks)
                a[mf * 2 + ks] = *fragp(bufA, wm * 128 + mf * 16 + l16, ks, quad);
#pragma unroll
        for (int nf = 0; nf < 2; ++nf)
#pragma unroll
            for (int ks = 0; ks < 2; ++ks)
                bl[nf * 2 + ks] = *fragp(bufB, wn * 64 + nf * 16 + l16, ks, quad);
        stage_ht(Ap, Bp, K, NT, lds0, pbase + 0, tid);
        __builtin_amdgcn_s_barrier();
        asm volatile("s_waitcnt lgkmcnt(0)");
        __builtin_amdgcn_s_setprio(1);
#pragma unroll
        for (int mf = 0; mf < 4; ++mf)
#pragma unroll
            for (int nf = 0; nf < 2; ++nf)
#pragma unroll
                for (int ks = 0; ks < 2; ++ks)
                    acc[mf][nf] = __builtin_amdgcn_mfma_f32_16x16x32_bf16(
                        a[mf * 2 + ks], bl[nf * 2 + ks], acc[mf][nf], 0, 0, 0);
        __builtin_amdgcn_s_setprio(0);
        __builtin_amdgcn_s_barrier();

        // ---- P1: read B(nf2-3) [4 rds]; stage Aks1(t+1); Q(m-lo,n-hi)
#pragma unroll
        for (int nf = 0; nf < 2; ++nf)
#pragma unroll
            for (int ks = 0; ks < 2; ++ks)
                bh[nf * 2 + ks] = *fragp(bufB, wn * 64 + (nf + 2) * 16 + l16, ks, quad);
        stage_ht(Ap, Bp, K, NT, lds0, pbase + 1, tid);
        __builtin_amdgcn_s_barrier();
        asm volatile("s_waitcnt lgkmcnt(0)");
        __builtin_amdgcn_s_setprio(1);
#pragma unroll
        for (int mf = 0; mf < 4; ++mf)
#pragma unroll
            for (int nf = 0; nf < 2; ++nf)
#pragma unroll
                for (int ks = 0; ks < 2; ++ks)
                    acc[mf][nf + 2] = __builtin_amdgcn_mfma_f32_16x16x32_bf16(
                        a[mf * 2 + ks], bh[nf * 2 + ks], acc[mf][nf + 2], 0, 0, 0);
        __builtin_amdgcn_s_setprio(0);
        __builtin_amdgcn_s_barrier();

        // ---- P2: read A(mf4-7) [8 rds]; stage Bks0(t+2); Q(m-hi,n-hi)
#pragma unroll
        for (int mf = 0; mf < 4; ++mf)
#pragma unroll
            for (int ks = 0; ks < 2; ++ks)
                a[mf * 2 + ks] = *fragp(bufA, wm * 128 + (mf + 4) * 16 + l16, ks, quad);
        stage_ht(Ap, Bp, K, NT, lds0, pbase + 2, tid);
        __builtin_amdgcn_s_barrier();
        asm volatile("s_waitcnt lgkmcnt(0)");
        __builtin_amdgcn_s_setprio(1);
#pragma unroll
        for (int mf = 0; mf < 4; ++mf)
#pragma unroll
            for (int nf = 0; nf < 2; ++nf)
#pragma unroll
                for (int ks = 0; ks < 2; ++ks)
                    acc[mf + 4][nf + 2] = __builtin_amdgcn_mfma_f32_16x16x32_bf16(
                        a[mf * 2 + ks], bh[nf * 2 + ks], acc[mf + 4][nf + 2], 0, 0, 0);
        __builtin_amdgcn_s_setprio(0);
        __builtin_amdgcn_s_barrier();

        // ---- P3: no reads; stage Bks1(t+2); Q(m-hi,n-lo); counted vmcnt
        stage_ht(Ap, Bp, K, NT, lds0, pbase + 3, tid);
        __builtin_amdgcn_s_setprio(1);
#pragma unroll
        for (int mf = 0; mf < 4; ++mf)
#pragma unroll
            for (int nf = 0; nf < 2; ++nf)
#pragma unroll
                for (int ks = 0; ks < 2; ++ks)
                    acc[mf + 4][nf] = __builtin_amdgcn_mfma_f32_16x16x32_bf16(
                        a[mf * 2 + ks], bl[nf * 2 + ks], acc[mf + 4][nf], 0, 0, 0);
        __builtin_amdgcn_s_setprio(0);
        asm volatile("s_waitcnt vmcnt(4)");      // tile t+1 resident; 2 units in flight
        __builtin_amdgcn_s_barrier();
    }
}

// GEMM1: H = gelu_exact(Xg @ w1t^T + b1), bf16 out.
__global__ __launch_bounds__(512, 2) void gemm1_kernel(const bf16_t* __restrict__ Xg,
                                                       const bf16_t* __restrict__ w1t,
                                                       const float* __restrict__ b1,
                                                       bf16_t* __restrict__ H) {
    extern __shared__ char lds0[];
    const int bn = blockIdx.x, bm = blockIdx.y;
    const int e = bm / (CAP / 256);
    const bf16_t* Ap = Xg + (size_t)bm * 256 * EMB_D;
    const bf16_t* Bp = w1t + ((size_t)e * HID_H + bn * 256) * EMB_D;
    f32x4 acc[8][4];
    const f32x4 z4 = {0.f, 0.f, 0.f, 0.f};
#pragma unroll
    for (int i = 0; i < 8; i++)
#pragma unroll
        for (int j = 0; j < 4; j++) acc[i][j] = z4;

    mainloop256<EMB_D / 64>(Ap, Bp, lds0, acc);

    const int tid = threadIdx.x;
    const int lane = tid & 63, wid = tid >> 6;
    const int wm = wid >> 2, wn = wid & 3;
    const int quad = lane >> 4, l16 = lane & 15;
#pragma unroll
    for (int nf = 0; nf < 4; ++nf) {
        const int col = bn * 256 + wn * 64 + nf * 16 + l16;
        const float bias = b1[e * HID_H + col];
#pragma unroll
        for (int mf = 0; mf < 8; ++mf) {
            const int row = bm * 256 + wm * 128 + mf * 16 + quad * 4;
#pragma unroll
            for (int r = 0; r < 4; ++r) {
                const float v = acc[mf][nf][r] + bias;
                const float g = 0.5f * v * (1.f + erff(v * 0.7071067811865475f));
                H[(size_t)(row + r) * HID_H + col] = (bf16_t)g;
            }
        }
    }
}

// GEMM2: Yg = H @ w2t^T (bf16, dense; bias added in combine).
__global__ __launch_bounds__(512, 2) void gemm2_kernel(const bf16_t* __restrict__ H,
                                                       const bf16_t* __restrict__ w2t,
                                                       bf16_t* __restrict__ Yg) {
    extern __shared__ char lds0[];
    const int bn = blockIdx.x, bm = blockIdx.y;
    const int e = bm / (CAP / 256);
    const bf16_t* Ap = H + (size_t)bm * 256 * HID_H;
    const bf16_t* Bp = w2t + ((size_t)e * EMB_D + bn * 256) * HID_H;
    f32x4 acc[8][4];
    const f32x4 z4 = {0.f, 0.f, 0.f, 0.f};
#pragma unroll
    for (int i = 0; i < 8; i++)
#pragma unroll
        for (int j = 0; j < 4; j++) acc[i][j] = z4;

    mainloop256<HID_H / 64>(Ap, Bp, lds0, acc);

    const int tid = threadIdx.x;
    const int lane = tid & 63, wid = tid >> 6;
    const int wm = wid >> 2, wn = wid & 3;
    const int quad = lane >> 4, l16 = lane & 15;
#pragma unroll
    for (int nf = 0; nf < 4; ++nf) {
        const int col = bn * 256 + wn * 64 + nf * 16 + l16;
#pragma unroll
        for (int mf = 0; mf < 8; ++mf) {
            const int row = bm * 256 + wm * 128 + mf * 16 + quad * 4;
#pragma unroll
            for (int r = 0; r < 4; ++r)
                Yg[(size_t)(row + r) * EMB_D + col] = (bf16_t)acc[mf][nf][r];
        }
    }
}

// =====================================================================
// Combine: out[t] = sum over kept slots (Yg[row] + b2[expert]) ; 0 if dropped
// =====================================================================
__global__ void combine_kernel(const bf16_t* __restrict__ Yg, const float* __restrict__ b2,
                               const int* __restrict__ inv, float* __restrict__ out) {
    const int t = blockIdx.x;
    const int tid = threadIdx.x;   // 128, 8 floats each
    const int d = tid * 8;
    const int r0 = inv[t * 2], r1 = inv[t * 2 + 1];
    float acc[8];
#pragma unroll
    for (int i = 0; i < 8; i++) acc[i] = 0.f;
    if (r0 >= 0) {
        const int e = r0 / CAP;
        const bf16x8 v = *(const bf16x8*)(Yg + (size_t)r0 * EMB_D + d);
        const float* bp = b2 + e * EMB_D + d;
#pragma unroll
        for (int i = 0; i < 8; i++) acc[i] += (float)v[i] + bp[i];
    }
    if (r1 >= 0) {
        const int e = r1 / CAP;
        const bf16x8 v = *(const bf16x8*)(Yg + (size_t)r1 * EMB_D + d);
        const float* bp = b2 + e * EMB_D + d;
#pragma unroll
        for (int i = 0; i < 8; i++) acc[i] += (float)v[i] + bp[i];
    }
    float4 o0 = {acc[0], acc[1], acc[2], acc[3]};
    float4 o1 = {acc[4], acc[5], acc[6], acc[7]};
    *(float4*)(out + (size_t)t * EMB_D + d)     = o0;
    *(float4*)(out + (size_t)t * EMB_D + d + 4) = o1;
}

// =====================================================================
// Finalize: loss = E*sum(load^2) + 0.001*mean(logits^2); usage floats.
// =====================================================================
__global__ void finalize_kernel(const int* __restrict__ usage, const float* __restrict__ zsum,
                                float* __restrict__ out) {
    if (threadIdx.x == 0) {
        float u[NEXP], s = 0.f;
        for (int e = 0; e < NEXP; e++) { u[e] = (float)usage[e]; s += u[e]; }
        const float inv = 1.f / (s + 1e-6f);
        float bal = 0.f;
        for (int e = 0; e < NEXP; e++) { const float l = u[e] * inv; bal += l * l; }
        bal *= (float)NEXP;
        const float z = 0.001f * zsum[0] / (float)((size_t)NTOK * NEXP);
        out[(size_t)NTOK * EMB_D] = bal + z;
        for (int e = 0; e < NEXP; e++) out[(size_t)NTOK * EMB_D + 1 + e] = u[e];
    }
}

extern "C" void kernel_launch(void* const* d_in, const int* in_sizes, int n_in,
                              void* d_out, int out_size, void* d_ws, size_t ws_size,
                              hipStream_t stream) {
    (void)in_sizes; (void)n_in; (void)out_size;
    const float* x  = (const float*)d_in[0];
    const float* wr = (const float*)d_in[1];
    const float* br = (const float*)d_in[2];
    const float* w1 = (const float*)d_in[3];
    const float* b1 = (const float*)d_in[4];
    const float* w2 = (const float*)d_in[5];
    const float* b2 = (const float*)d_in[6];
    float* out = (float*)d_out;

    uint8_t* ws = (uint8_t*)d_ws;
    size_t off = 0;
    auto carve = [&](size_t bytes) -> void* {
        off = (off + 255) & ~(size_t)255;
        void* p = ws + off;
        off += bytes;
        return p;
    };
    float*  zsum  = (float*)carve(sizeof(float));
    int*    usage = (int*)carve(NEXP * sizeof(int));
    int*    counts = (int*)carve((size_t)NCHUNK * NEXP * sizeof(int));
    int*    base   = (int*)carve((size_t)NCHUNK * NEXP * sizeof(int));
    int2*   top2 = (int2*)carve((size_t)NTOK * sizeof(int2));
    int*    buf  = (int*)carve((size_t)MROWS * sizeof(int));
    int*    inv  = (int*)carve((size_t)NTOK * 2 * sizeof(int));
    bf16_t* Xg   = (bf16_t*)carve((size_t)MROWS * EMB_D * sizeof(bf16_t));
    bf16_t* w1t  = (bf16_t*)carve((size_t)NEXP * HID_H * EMB_D * sizeof(bf16_t));
    bf16_t* w2t  = (bf16_t*)carve((size_t)NEXP * EMB_D * HID_H * sizeof(bf16_t));
    bf16_t* H    = (bf16_t*)carve((size_t)MROWS * HID_H * sizeof(bf16_t));
    bf16_t* Yg   = Xg;   // Xg is dead after gemm1 -> reuse for gemm2 output
    if (off > ws_size) return;   // workspace too small: fail loudly

    static bool attr_set = false;
    if (!attr_set) {
        hipFuncSetAttribute(reinterpret_cast<const void*>(&gemm1_kernel),
                            hipFuncAttributeMaxDynamicSharedMemorySize, LDS_TOTAL);
        hipFuncSetAttribute(reinterpret_cast<const void*>(&gemm2_kernel),
                            hipFuncAttributeMaxDynamicSharedMemorySize, LDS_TOTAL);
        attr_set = true;
    }

    hipMemsetAsync(zsum, 0, sizeof(float), stream);

    router_kernel<<<NTOK / 4, 256, 0, stream>>>(x, wr, br, top2, zsum);
    count_kernel<<<NCHUNK, 1024, 0, stream>>>(top2, counts);
    prefix_kernel<<<1, 64, 0, stream>>>(counts, base, usage);
    place_kernel<<<NCHUNK, 1024, 0, stream>>>(top2, base, buf, inv);
    pad_kernel<<<NEXP, 256, 0, stream>>>(usage, buf);
    gather_kernel<<<MROWS, 128, 0, stream>>>(x, buf, Xg);
    transpose_conv_kernel<<<dim3(HID_H / 64, EMB_D / 64, NEXP), 256, 0, stream>>>(w1, w1t, EMB_D, HID_H);
    transpose_conv_kernel<<<dim3(EMB_D / 64, HID_H / 64, NEXP), 256, 0, stream>>>(w2, w2t, HID_H, EMB_D);
    gemm1_kernel<<<dim3(HID_H / 256, MROWS / 256), 512, LDS_TOTAL, stream>>>(Xg, w1t, b1, H);
    gemm2_kernel<<<dim3(EMB_D / 256, MROWS / 256), 512, LDS_TOTAL, stream>>>(H, w2t, Yg);
    combine_kernel<<<NTOK, 128, 0, stream>>>(Yg, b2, inv, out);
    finalize_kernel<<<1, 64, 0, stream>>>(usage, zsum, out);
}

// Round 3
// 907.642 us; speedup vs baseline: 1.0689x; 1.0274x over previous
//
#include <hip/hip_runtime.h>
#include <cstdint>

// ---- problem constants (B=8,T=4096 -> N=32768; EMB=1024; HID=2048; E=8; k=2) ----
#define NTOK   32768
#define EMB_D  1024
#define HID_H  2048
#define NEXP   8
#define CAP    5120               // int(1.25 * 32768 / 8)
#define MROWS  (NEXP * CAP)       // 40960 expert-buffer rows total
#define NCHUNK 32                 // token chunks for parallel scan (1024 tokens each)

typedef __bf16 bf16_t;
typedef bf16_t bf16x8 __attribute__((ext_vector_type(8)));
typedef float  f32x4  __attribute__((ext_vector_type(4)));

typedef __attribute__((address_space(3))) void       lds_void_t;
typedef const __attribute__((address_space(1))) void g_void_t;

__device__ __forceinline__ void gload_lds16(const void* g, void* l) {
    __builtin_amdgcn_global_load_lds((g_void_t*)(uintptr_t)g,
                                     (lds_void_t*)(uint32_t)(uintptr_t)l, 16, 0, 0);
}

// =====================================================================
// Router: logits = x@wr + br ; z-loss partials ; softmax ; top-2
// =====================================================================
__global__ void router_kernel(const float* __restrict__ x, const float* __restrict__ wr,
                              const float* __restrict__ br, int2* __restrict__ top2,
                              float* __restrict__ zsum) {
    __shared__ float s_wr[NEXP * EMB_D];   // [e][d], 32 KB
    __shared__ float s_z[4];
    const int tid = threadIdx.x;           // 256
    for (int i = tid; i < NEXP * EMB_D; i += 256) {
        int d = i >> 3, e = i & 7;         // wr is [d][e] row-major
        s_wr[e * EMB_D + d] = wr[i];
    }
    __syncthreads();
    const int wid = tid >> 6, lane = tid & 63;
    const int t = blockIdx.x * 4 + wid;
    const float* xr = x + (size_t)t * EMB_D;

    float acc[NEXP];
#pragma unroll
    for (int e = 0; e < NEXP; e++) acc[e] = 0.f;
#pragma unroll
    for (int it = 0; it < EMB_D / 64; ++it) {
        float xv = xr[lane + 64 * it];
#pragma unroll
        for (int e = 0; e < NEXP; e++) acc[e] += xv * s_wr[e * EMB_D + lane + 64 * it];
    }
#pragma unroll
    for (int e = 0; e < NEXP; e++) {
        float v = acc[e];
#pragma unroll
        for (int off = 32; off > 0; off >>= 1) v += __shfl_xor(v, off);
        acc[e] = v;
    }
    if (lane == 0) {
        float lg[NEXP]; float zs = 0.f;
#pragma unroll
        for (int e = 0; e < NEXP; e++) { lg[e] = acc[e] + br[e]; zs += lg[e] * lg[e]; }
        s_z[wid] = zs;
        float mx = lg[0];
        for (int e = 1; e < NEXP; e++) mx = fmaxf(mx, lg[e]);
        float p[NEXP]; float se = 0.f;
        for (int e = 0; e < NEXP; e++) { p[e] = expf(lg[e] - mx); se += p[e]; }
        for (int e = 0; e < NEXP; e++) p[e] = p[e] / se;
        int i0 = 0; float b0 = p[0];
        for (int e = 1; e < NEXP; e++) if (p[e] > b0) { b0 = p[e]; i0 = e; }
        int i1 = -1; float b1v = -1.f;
        for (int e = 0; e < NEXP; e++) if (e != i0 && p[e] > b1v) { b1v = p[e]; i1 = e; }
        top2[t] = make_int2(i0, i1);
    }
    __syncthreads();
    if (tid == 0) unsafeAtomicAdd(zsum, s_z[0] + s_z[1] + s_z[2] + s_z[3]);
}

// =====================================================================
// Parallel capacity scan: count -> prefix -> place (+inverse map) -> pad
// =====================================================================
__global__ void count_kernel(const int2* __restrict__ top2, int* __restrict__ counts) {
    const int chunk = blockIdx.x;          // 32 chunks x 1024 tokens
    const int tid = threadIdx.x;           // 1024
    const int wid = tid >> 6, lane = tid & 63;
    __shared__ int wcnt[NEXP][16];
    const int2 tp = top2[chunk * 1024 + tid];
#pragma unroll
    for (int e = 0; e < NEXP; e++) {
        const bool m = (tp.x == e) || (tp.y == e);
        unsigned long long bal = __ballot(m);
        if (lane == 0) wcnt[e][wid] = __popcll(bal);
    }
    __syncthreads();
    if (tid < NEXP) {
        int s = 0;
        for (int w = 0; w < 16; w++) s += wcnt[tid][w];
        counts[chunk * NEXP + tid] = s;
    }
}

__global__ void prefix_kernel(const int* __restrict__ counts, int* __restrict__ base,
                              int* __restrict__ usage) {
    const int e = threadIdx.x;
    if (e < NEXP) {
        int run = 0;
        for (int c = 0; c < NCHUNK; c++) {
            base[c * NEXP + e] = run;
            run += counts[c * NEXP + e];
        }
        usage[e] = run < CAP ? run : CAP;
    }
}

__global__ void place_kernel(const int2* __restrict__ top2, const int* __restrict__ base,
                             int* __restrict__ buf, int* __restrict__ inv) {
    const int chunk = blockIdx.x;
    const int tid = threadIdx.x;           // 1024
    const int wid = tid >> 6, lane = tid & 63;
    const int t = chunk * 1024 + tid;
    __shared__ int wpre[NEXP][16];
    const int2 tp = top2[t];
    int lpre[NEXP]; bool mm[NEXP];
#pragma unroll
    for (int e = 0; e < NEXP; e++) {
        mm[e] = (tp.x == e) || (tp.y == e);
        unsigned long long bal = __ballot(mm[e]);
        lpre[e] = __popcll(bal & ((1ull << lane) - 1ull));
        if (lane == 0) wpre[e][wid] = __popcll(bal);
    }
    __syncthreads();
    if (tid < NEXP) {
        int a = 0;
        for (int w = 0; w < 16; w++) { int v = wpre[tid][w]; wpre[tid][w] = a; a += v; }
    }
    __syncthreads();
#pragma unroll
    for (int e = 0; e < NEXP; e++) {
        if (mm[e]) {
            const int pos = base[chunk * NEXP + e] + wpre[e][wid] + lpre[e];
            const int slot = (tp.x == e) ? 0 : 1;
            if (pos < CAP) {
                const int row = e * CAP + pos;
                buf[row] = t;
                inv[t * 2 + slot] = row;
            } else {
                inv[t * 2 + slot] = -1;
            }
        }
    }
}

__global__ void pad_kernel(const int* __restrict__ usage, int* __restrict__ buf) {
    const int e = blockIdx.x;
    const int u = usage[e];
    for (int p = u + threadIdx.x; p < CAP; p += blockDim.x) buf[e * CAP + p] = NTOK;
}

// =====================================================================
// Gather: Xg[row][d] = bf16(x[buf[row]][d])  (zero row for pad)
// =====================================================================
__global__ void gather_kernel(const float* __restrict__ x, const int* __restrict__ buf,
                              bf16_t* __restrict__ Xg) {
    const int row = blockIdx.x;
    const int t = buf[row];
    const int tid = threadIdx.x;   // 128, 8 elems each
    bf16x8 v;
    if (t >= 0 && t < NTOK) {
        const float* xr = x + (size_t)t * EMB_D + tid * 8;
        const float4 a = *(const float4*)(xr);
        const float4 b = *(const float4*)(xr + 4);
        v[0] = (bf16_t)a.x; v[1] = (bf16_t)a.y; v[2] = (bf16_t)a.z; v[3] = (bf16_t)a.w;
        v[4] = (bf16_t)b.x; v[5] = (bf16_t)b.y; v[6] = (bf16_t)b.z; v[7] = (bf16_t)b.w;
    } else {
#pragma unroll
        for (int i = 0; i < 8; i++) v[i] = (bf16_t)0.f;
    }
    *(bf16x8*)(Xg + (size_t)row * EMB_D + tid * 8) = v;
}

// =====================================================================
// Transpose + convert: in[e][R][C] fp32 -> out[e][C][R] bf16
// =====================================================================
__global__ void transpose_conv_kernel(const float* __restrict__ in, bf16_t* __restrict__ out,
                                      int R, int C) {
    __shared__ bf16_t tile[64][72];
    const int e = blockIdx.z;
    const int c0 = blockIdx.x * 64, r0 = blockIdx.y * 64;
    const float*  ip = in  + (size_t)e * R * C;
    bf16_t*       op = out + (size_t)e * R * C;
    const int tid = threadIdx.x;   // 256
    const int tr = tid >> 4;
    const int tc = (tid & 15) * 4;
#pragma unroll
    for (int rr = 0; rr < 64; rr += 16) {
        const float4 v = *(const float4*)(ip + (size_t)(r0 + tr + rr) * C + (c0 + tc));
        tile[tr + rr][tc + 0] = (bf16_t)v.x;
        tile[tr + rr][tc + 1] = (bf16_t)v.y;
        tile[tr + rr][tc + 2] = (bf16_t)v.z;
        tile[tr + rr][tc + 3] = (bf16_t)v.w;
    }
    __syncthreads();
    const int oc = tid >> 2;
    const int og = (tid & 3) * 16;
    bf16x8 v0, v1;
#pragma unroll
    for (int i = 0; i < 8; i++) v0[i] = tile[og + i][oc];
#pragma unroll
    for (int i = 0; i < 8; i++) v1[i] = tile[og + 8 + i][oc];
    *(bf16x8*)(op + (size_t)(c0 + oc) * R + r0 + og)     = v0;
    *(bf16x8*)(op + (size_t)(c0 + oc) * R + r0 + og + 8) = v1;
}

// =====================================================================
// 256x256 8-phase MFMA GEMM, 3-bit XOR swizzle (conflict-free ds_read_b128)
//   BM=BN=256, BK=64, 512 threads = 8 waves (2 M x 4 N), per-wave 128x64 out.
//   LDS: 2 buffers x (A 32KB + B 32KB) = 128 KB (dynamic).
//   Tile layout: [row][128B of K], fragment addr:
//     byte = row*128 + (((ks*4+quad) ^ (row&7)) << 4)
//   -> the 8 lanes of any ds_read service group cover 8 distinct 16B slots
//      (zero bank conflicts; 2-way under strided grouping = free per m136).
//   global_load_lds dest stays LINEAR; the SOURCE k-chunk is permuted by the
//   same involution: sq = (tid&7) ^ ((tid>>3)&7)  (both-sides rule).
//   Staging: half-tiles [B0,B1,A0,A1] of 16KB (128 rows); lead 6; per-tile-end
//   s_waitcnt vmcnt(4) = 2 half-tiles in flight (A(t+1) proven resident).
// =====================================================================
#define BUF_BYTES 65536
#define LDS_TOTAL 131072

__device__ __forceinline__ const bf16x8* fragp(const char* base, int row, int ks, int quad) {
    return (const bf16x8*)(base + row * 128 + ((((ks << 2) + quad) ^ (row & 7)) << 4));
}

// stage one 16KB half-tile: idx = 4*ktile + part, part order [B0,B1,A0,A1].
__device__ __forceinline__ void stage_ht(const bf16_t* __restrict__ Ap,
                                         const bf16_t* __restrict__ Bp,
                                         int K, int NT, char* lds0, int idx, int tid) {
    if (idx >= 4 * NT) return;
    const int t = idx >> 2, part = idx & 3;
    char* dst = lds0 + (t & 1) * BUF_BYTES + ((part < 2) ? 32768 : 0)
              + (part & 1) * 16384 + tid * 16;
    const int row0 = tid >> 3;                    // 0..63 (64 rows per gload)
    const int sq   = (tid & 7) ^ (row0 & 7);      // pre-swizzled 16B slot
    const bf16_t* src = ((part < 2) ? Bp : Ap)
                      + (size_t)((part & 1) * 128 + row0) * K + (size_t)t * 64 + sq * 8;
    gload_lds16(src, dst);                          // rows row0
    gload_lds16(src + (size_t)64 * K, dst + 8192);  // rows row0+64
}

template <int NT>
__device__ __forceinline__ void mainloop256(const bf16_t* __restrict__ Ap,
                                            const bf16_t* __restrict__ Bp,
                                            char* lds0, f32x4 (&acc)[8][4]) {
    const int K = NT * 64;
    const int tid = threadIdx.x;
    const int lane = tid & 63, wid = tid >> 6;
    const int wm = wid >> 2, wn = wid & 3;
    const int quad = lane >> 4, l16 = lane & 15;

    // prologue: tile0 fully + B halves of tile1 (6 units)
#pragma unroll
    for (int idx = 0; idx < 6; ++idx) stage_ht(Ap, Bp, K, NT, lds0, idx, tid);
    asm volatile("s_waitcnt vmcnt(4)" ::: "memory");   // tile0 resident (4 instrs = 2 units out)
    __builtin_amdgcn_s_barrier();

    bf16x8 a[8], bl[4], bh[4];
    for (int t = 0; t < NT; ++t) {
        const char* bufA = lds0 + (t & 1) * BUF_BYTES;
        const char* bufB = bufA + 32768;
        const int pbase = 4 * t + 6;

        // ---- P0: read A(mf0-3)+B(nf0-1) [12 rds]; stage A0(t+1); Q(m-lo,n-lo)
#pragma unroll
        for (int mf = 0; mf < 4; ++mf)
#pragma unroll
            for (int ks = 0; ks < 2; ++ks)
                a[mf * 2 + ks] = *fragp(bufA, wm * 128 + mf * 16 + l16, ks, quad);
#pragma unroll
        for (int nf = 0; nf < 2; ++nf)
#pragma unroll
            for (int ks = 0; ks < 2; ++ks)
                bl[nf * 2 + ks] = *fragp(bufB, wn * 64 + nf * 16 + l16, ks, quad);
        stage_ht(Ap, Bp, K, NT, lds0, pbase + 0, tid);
        __builtin_amdgcn_s_barrier();
        asm volatile("s_waitcnt lgkmcnt(0)" ::: "memory");
        __builtin_amdgcn_sched_barrier(0);           // rule 18: pin MFMA below the wait
        __builtin_amdgcn_s_setprio(1);
#pragma unroll
        for (int mf = 0; mf < 4; ++mf)
#pragma unroll
            for (int nf = 0; nf < 2; ++nf)
#pragma unroll
                for (int ks = 0; ks < 2; ++ks)
                    acc[mf][nf] = __builtin_amdgcn_mfma_f32_16x16x32_bf16(
                        a[mf * 2 + ks], bl[nf * 2 + ks], acc[mf][nf], 0, 0, 0);
        __builtin_amdgcn_s_setprio(0);
        __builtin_amdgcn_s_barrier();

        // ---- P1: read B(nf2-3) [4 rds]; stage A1(t+1); Q(m-lo,n-hi)
#pragma unroll
        for (int nf = 0; nf < 2; ++nf)
#pragma unroll
            for (int ks = 0; ks < 2; ++ks)
                bh[nf * 2 + ks] = *fragp(bufB, wn * 64 + (nf + 2) * 16 + l16, ks, quad);
        stage_ht(Ap, Bp, K, NT, lds0, pbase + 1, tid);
        __builtin_amdgcn_s_barrier();
        asm volatile("s_waitcnt lgkmcnt(0)" ::: "memory");
        __builtin_amdgcn_sched_barrier(0);
        __builtin_amdgcn_s_setprio(1);
#pragma unroll
        for (int mf = 0; mf < 4; ++mf)
#pragma unroll
            for (int nf = 0; nf < 2; ++nf)
#pragma unroll
                for (int ks = 0; ks < 2; ++ks)
                    acc[mf][nf + 2] = __builtin_amdgcn_mfma_f32_16x16x32_bf16(
                        a[mf * 2 + ks], bh[nf * 2 + ks], acc[mf][nf + 2], 0, 0, 0);
        __builtin_amdgcn_s_setprio(0);
        __builtin_amdgcn_s_barrier();

        // ---- P2: read A(mf4-7) [8 rds]; stage B0(t+2); Q(m-hi,n-hi)
#pragma unroll
        for (int mf = 0; mf < 4; ++mf)
#pragma unroll
            for (int ks = 0; ks < 2; ++ks)
                a[mf * 2 + ks] = *fragp(bufA, wm * 128 + (mf + 4) * 16 + l16, ks, quad);
        stage_ht(Ap, Bp, K, NT, lds0, pbase + 2, tid);
        __builtin_amdgcn_s_barrier();
        asm volatile("s_waitcnt lgkmcnt(0)" ::: "memory");
        __builtin_amdgcn_sched_barrier(0);
        __builtin_amdgcn_s_setprio(1);
#pragma unroll
        for (int mf = 0; mf < 4; ++mf)
#pragma unroll
            for (int nf = 0; nf < 2; ++nf)
#pragma unroll
                for (int ks = 0; ks < 2; ++ks)
                    acc[mf + 4][nf + 2] = __builtin_amdgcn_mfma_f32_16x16x32_bf16(
                        a[mf * 2 + ks], bh[nf * 2 + ks], acc[mf + 4][nf + 2], 0, 0, 0);
        __builtin_amdgcn_s_setprio(0);
        __builtin_amdgcn_s_barrier();

        // ---- P3: no reads; stage B1(t+2); Q(m-hi,n-lo); counted vmcnt
        stage_ht(Ap, Bp, K, NT, lds0, pbase + 3, tid);
        __builtin_amdgcn_s_setprio(1);
#pragma unroll
        for (int mf = 0; mf < 4; ++mf)
#pragma unroll
            for (int nf = 0; nf < 2; ++nf)
#pragma unroll
                for (int ks = 0; ks < 2; ++ks)
                    acc[mf + 4][nf] = __builtin_amdgcn_mfma_f32_16x16x32_bf16(
                        a[mf * 2 + ks], bl[nf * 2 + ks], acc[mf + 4][nf], 0, 0, 0);
        __builtin_amdgcn_s_setprio(0);
        asm volatile("s_waitcnt vmcnt(4)" ::: "memory");  // A(t+1),B(t+1) resident; B(t+2) in flight
        __builtin_amdgcn_s_barrier();
    }
}

// GEMM1: H = gelu_exact(Xg @ w1t^T + b1), bf16 out.
__global__ __launch_bounds__(512, 2) void gemm1_kernel(const bf16_t* __restrict__ Xg,
                                                       const bf16_t* __restrict__ w1t,
                                                       const float* __restrict__ b1,
                                                       bf16_t* __restrict__ H) {
    extern __shared__ char lds0[];
    const int bn = blockIdx.x, bm = blockIdx.y;
    const int e = bm / (CAP / 256);
    const bf16_t* Ap = Xg + (size_t)bm * 256 * EMB_D;
    const bf16_t* Bp = w1t + ((size_t)e * HID_H + bn * 256) * EMB_D;
    f32x4 acc[8][4];
    const f32x4 z4 = {0.f, 0.f, 0.f, 0.f};
#pragma unroll
    for (int i = 0; i < 8; i++)
#pragma unroll
        for (int j = 0; j < 4; j++) acc[i][j] = z4;

    mainloop256<EMB_D / 64>(Ap, Bp, lds0, acc);

    const int tid = threadIdx.x;
    const int lane = tid & 63, wid = tid >> 6;
    const int wm = wid >> 2, wn = wid & 3;
    const int quad = lane >> 4, l16 = lane & 15;
#pragma unroll
    for (int nf = 0; nf < 4; ++nf) {
        const int col = bn * 256 + wn * 64 + nf * 16 + l16;
        const float bias = b1[e * HID_H + col];
#pragma unroll
        for (int mf = 0; mf < 8; ++mf) {
            const int row = bm * 256 + wm * 128 + mf * 16 + quad * 4;
#pragma unroll
            for (int r = 0; r < 4; ++r) {
                const float v = acc[mf][nf][r] + bias;
                const float g = 0.5f * v * (1.f + erff(v * 0.7071067811865475f));
                H[(size_t)(row + r) * HID_H + col] = (bf16_t)g;
            }
        }
    }
}

// GEMM2: Yg = H @ w2t^T (bf16, dense; bias added in combine).
__global__ __launch_bounds__(512, 2) void gemm2_kernel(const bf16_t* __restrict__ H,
                                                       const bf16_t* __restrict__ w2t,
                                                       bf16_t* __restrict__ Yg) {
    extern __shared__ char lds0[];
    const int bn = blockIdx.x, bm = blockIdx.y;
    const int e = bm / (CAP / 256);
    const bf16_t* Ap = H + (size_t)bm * 256 * HID_H;
    const bf16_t* Bp = w2t + ((size_t)e * EMB_D + bn * 256) * HID_H;
    f32x4 acc[8][4];
    const f32x4 z4 = {0.f, 0.f, 0.f, 0.f};
#pragma unroll
    for (int i = 0; i < 8; i++)
#pragma unroll
        for (int j = 0; j < 4; j++) acc[i][j] = z4;

    mainloop256<HID_H / 64>(Ap, Bp, lds0, acc);

    const int tid = threadIdx.x;
    const int lane = tid & 63, wid = tid >> 6;
    const int wm = wid >> 2, wn = wid & 3;
    const int quad = lane >> 4, l16 = lane & 15;
#pragma unroll
    for (int nf = 0; nf < 4; ++nf) {
        const int col = bn * 256 + wn * 64 + nf * 16 + l16;
#pragma unroll
        for (int mf = 0; mf < 8; ++mf) {
            const int row = bm * 256 + wm * 128 + mf * 16 + quad * 4;
#pragma unroll
            for (int r = 0; r < 4; ++r)
                Yg[(size_t)(row + r) * EMB_D + col] = (bf16_t)acc[mf][nf][r];
        }
    }
}

// =====================================================================
// Combine: out[t] = sum over kept slots (Yg[row] + b2[expert]) ; 0 if dropped
// =====================================================================
__global__ void combine_kernel(const bf16_t* __restrict__ Yg, const float* __restrict__ b2,
                               const int* __restrict__ inv, float* __restrict__ out) {
    const int t = blockIdx.x;
    const int tid = threadIdx.x;   // 128, 8 floats each
    const int d = tid * 8;
    const int r0 = inv[t * 2], r1 = inv[t * 2 + 1];
    float acc[8];
#pragma unroll
    for (int i = 0; i < 8; i++) acc[i] = 0.f;
    if (r0 >= 0) {
        const int e = r0 / CAP;
        const bf16x8 v = *(const bf16x8*)(Yg + (size_t)r0 * EMB_D + d);
        const float* bp = b2 + e * EMB_D + d;
#pragma unroll
        for (int i = 0; i < 8; i++) acc[i] += (float)v[i] + bp[i];
    }
    if (r1 >= 0) {
        const int e = r1 / CAP;
        const bf16x8 v = *(const bf16x8*)(Yg + (size_t)r1 * EMB_D + d);
        const float* bp = b2 + e * EMB_D + d;
#pragma unroll
        for (int i = 0; i < 8; i++) acc[i] += (float)v[i] + bp[i];
    }
    float4 o0 = {acc[0], acc[1], acc[2], acc[3]};
    float4 o1 = {acc[4], acc[5], acc[6], acc[7]};
    *(float4*)(out + (size_t)t * EMB_D + d)     = o0;
    *(float4*)(out + (size_t)t * EMB_D + d + 4) = o1;
}

// =====================================================================
// Finalize: loss = E*sum(load^2) + 0.001*mean(logits^2); usage floats.
// =====================================================================
__global__ void finalize_kernel(const int* __restrict__ usage, const float* __restrict__ zsum,
                                float* __restrict__ out) {
    if (threadIdx.x == 0) {
        float u[NEXP], s = 0.f;
        for (int e = 0; e < NEXP; e++) { u[e] = (float)usage[e]; s += u[e]; }
        const float inv = 1.f / (s + 1e-6f);
        float bal = 0.f;
        for (int e = 0; e < NEXP; e++) { const float l = u[e] * inv; bal += l * l; }
        bal *= (float)NEXP;
        const float z = 0.001f * zsum[0] / (float)((size_t)NTOK * NEXP);
        out[(size_t)NTOK * EMB_D] = bal + z;
        for (int e = 0; e < NEXP; e++) out[(size_t)NTOK * EMB_D + 1 + e] = u[e];
    }
}

extern "C" void kernel_launch(void* const* d_in, const int* in_sizes, int n_in,
                              void* d_out, int out_size, void* d_ws, size_t ws_size,
                              hipStream_t stream) {
    (void)in_sizes; (void)n_in; (void)out_size;
    const float* x  = (const float*)d_in[0];
    const float* wr = (const float*)d_in[1];
    const float* br = (const float*)d_in[2];
    const float* w1 = (const float*)d_in[3];
    const float* b1 = (const float*)d_in[4];
    const float* w2 = (const float*)d_in[5];
    const float* b2 = (const float*)d_in[6];
    float* out = (float*)d_out;

    uint8_t* ws = (uint8_t*)d_ws;
    size_t off = 0;
    auto carve = [&](size_t bytes) -> void* {
        off = (off + 255) & ~(size_t)255;
        void* p = ws + off;
        off += bytes;
        return p;
    };
    float*  zsum  = (float*)carve(sizeof(float));
    int*    usage = (int*)carve(NEXP * sizeof(int));
    int*    counts = (int*)carve((size_t)NCHUNK * NEXP * sizeof(int));
    int*    base   = (int*)carve((size_t)NCHUNK * NEXP * sizeof(int));
    int2*   top2 = (int2*)carve((size_t)NTOK * sizeof(int2));
    int*    buf  = (int*)carve((size_t)MROWS * sizeof(int));
    int*    inv  = (int*)carve((size_t)NTOK * 2 * sizeof(int));
    bf16_t* Xg   = (bf16_t*)carve((size_t)MROWS * EMB_D * sizeof(bf16_t));
    bf16_t* w1t  = (bf16_t*)carve((size_t)NEXP * HID_H * EMB_D * sizeof(bf16_t));
    bf16_t* w2t  = (bf16_t*)carve((size_t)NEXP * EMB_D * HID_H * sizeof(bf16_t));
    bf16_t* H    = (bf16_t*)carve((size_t)MROWS * HID_H * sizeof(bf16_t));
    bf16_t* Yg   = Xg;   // Xg is dead after gemm1 -> reuse for gemm2 output
    if (off > ws_size) return;   // workspace too small: fail loudly

    static bool attr_set = false;
    if (!attr_set) {
        hipFuncSetAttribute(reinterpret_cast<const void*>(&gemm1_kernel),
                            hipFuncAttributeMaxDynamicSharedMemorySize, LDS_TOTAL);
        hipFuncSetAttribute(reinterpret_cast<const void*>(&gemm2_kernel),
                            hipFuncAttributeMaxDynamicSharedMemorySize, LDS_TOTAL);
        attr_set = true;
    }

    hipMemsetAsync(zsum, 0, sizeof(float), stream);

    router_kernel<<<NTOK / 4, 256, 0, stream>>>(x, wr, br, top2, zsum);
    count_kernel<<<NCHUNK, 1024, 0, stream>>>(top2, counts);
    prefix_kernel<<<1, 64, 0, stream>>>(counts, base, usage);
    place_kernel<<<NCHUNK, 1024, 0, stream>>>(top2, base, buf, inv);
    pad_kernel<<<NEXP, 256, 0, stream>>>(usage, buf);
    gather_kernel<<<MROWS, 128, 0, stream>>>(x, buf, Xg);
    transpose_conv_kernel<<<dim3(HID_H / 64, EMB_D / 64, NEXP), 256, 0, stream>>>(w1, w1t, EMB_D, HID_H);
    transpose_conv_kernel<<<dim3(EMB_D / 64, HID_H / 64, NEXP), 256, 0, stream>>>(w2, w2t, HID_H, EMB_D);
    gemm1_kernel<<<dim3(HID_H / 256, MROWS / 256), 512, LDS_TOTAL, stream>>>(Xg, w1t, b1, H);
    gemm2_kernel<<<dim3(EMB_D / 256, MROWS / 256), 512, LDS_TOTAL, stream>>>(H, w2t, Yg);
    combine_kernel<<<NTOK, 128, 0, stream>>>(Yg, b2, inv, out);
    finalize_kernel<<<1, 64, 0, stream>>>(usage, zsum, out);
}

// Round 4
// 861.865 us; speedup vs baseline: 1.1257x; 1.0531x over previous
//
#include <hip/hip_runtime.h>
#include <cstdint>

// ---- problem constants (B=8,T=4096 -> N=32768; EMB=1024; HID=2048; E=8; k=2) ----
#define NTOK   32768
#define EMB_D  1024
#define HID_H  2048
#define NEXP   8
#define CAP    5120               // int(1.25 * 32768 / 8)
#define MROWS  (NEXP * CAP)       // 40960 expert-buffer rows total
#define NCHUNK 32                 // token chunks for parallel scan (1024 tokens each)

typedef __bf16 bf16_t;
typedef bf16_t bf16x8 __attribute__((ext_vector_type(8)));
typedef float  f32x4  __attribute__((ext_vector_type(4)));

typedef __attribute__((address_space(3))) void       lds_void_t;
typedef const __attribute__((address_space(1))) void g_void_t;

__device__ __forceinline__ void gload_lds16(const void* g, void* l) {
    __builtin_amdgcn_global_load_lds((g_void_t*)(uintptr_t)g,
                                     (lds_void_t*)(uint32_t)(uintptr_t)l, 16, 0, 0);
}

// =====================================================================
// Router: logits = x@wr + br ; z-loss partials ; softmax ; top-2
// =====================================================================
__global__ void router_kernel(const float* __restrict__ x, const float* __restrict__ wr,
                              const float* __restrict__ br, int2* __restrict__ top2,
                              float* __restrict__ zsum) {
    __shared__ float s_wr[NEXP * EMB_D];   // [e][d], 32 KB
    __shared__ float s_z[4];
    const int tid = threadIdx.x;           // 256
    for (int i = tid; i < NEXP * EMB_D; i += 256) {
        int d = i >> 3, e = i & 7;         // wr is [d][e] row-major
        s_wr[e * EMB_D + d] = wr[i];
    }
    __syncthreads();
    const int wid = tid >> 6, lane = tid & 63;
    const int t = blockIdx.x * 4 + wid;
    const float* xr = x + (size_t)t * EMB_D;

    float acc[NEXP];
#pragma unroll
    for (int e = 0; e < NEXP; e++) acc[e] = 0.f;
#pragma unroll
    for (int it = 0; it < EMB_D / 64; ++it) {
        float xv = xr[lane + 64 * it];
#pragma unroll
        for (int e = 0; e < NEXP; e++) acc[e] += xv * s_wr[e * EMB_D + lane + 64 * it];
    }
#pragma unroll
    for (int e = 0; e < NEXP; e++) {
        float v = acc[e];
#pragma unroll
        for (int off = 32; off > 0; off >>= 1) v += __shfl_xor(v, off);
        acc[e] = v;
    }
    if (lane == 0) {
        float lg[NEXP]; float zs = 0.f;
#pragma unroll
        for (int e = 0; e < NEXP; e++) { lg[e] = acc[e] + br[e]; zs += lg[e] * lg[e]; }
        s_z[wid] = zs;
        float mx = lg[0];
        for (int e = 1; e < NEXP; e++) mx = fmaxf(mx, lg[e]);
        float p[NEXP]; float se = 0.f;
        for (int e = 0; e < NEXP; e++) { p[e] = expf(lg[e] - mx); se += p[e]; }
        for (int e = 0; e < NEXP; e++) p[e] = p[e] / se;
        int i0 = 0; float b0 = p[0];
        for (int e = 1; e < NEXP; e++) if (p[e] > b0) { b0 = p[e]; i0 = e; }
        int i1 = -1; float b1v = -1.f;
        for (int e = 0; e < NEXP; e++) if (e != i0 && p[e] > b1v) { b1v = p[e]; i1 = e; }
        top2[t] = make_int2(i0, i1);
    }
    __syncthreads();
    if (tid == 0) unsafeAtomicAdd(zsum, s_z[0] + s_z[1] + s_z[2] + s_z[3]);
}

// =====================================================================
// Parallel capacity scan: count -> prefix -> place (+inverse map) -> pad
// =====================================================================
__global__ void count_kernel(const int2* __restrict__ top2, int* __restrict__ counts) {
    const int chunk = blockIdx.x;          // 32 chunks x 1024 tokens
    const int tid = threadIdx.x;           // 1024
    const int wid = tid >> 6, lane = tid & 63;
    __shared__ int wcnt[NEXP][16];
    const int2 tp = top2[chunk * 1024 + tid];
#pragma unroll
    for (int e = 0; e < NEXP; e++) {
        const bool m = (tp.x == e) || (tp.y == e);
        unsigned long long bal = __ballot(m);
        if (lane == 0) wcnt[e][wid] = __popcll(bal);
    }
    __syncthreads();
    if (tid < NEXP) {
        int s = 0;
        for (int w = 0; w < 16; w++) s += wcnt[tid][w];
        counts[chunk * NEXP + tid] = s;
    }
}

__global__ void prefix_kernel(const int* __restrict__ counts, int* __restrict__ base,
                              int* __restrict__ usage) {
    const int e = threadIdx.x;
    if (e < NEXP) {
        int run = 0;
        for (int c = 0; c < NCHUNK; c++) {
            base[c * NEXP + e] = run;
            run += counts[c * NEXP + e];
        }
        usage[e] = run < CAP ? run : CAP;
    }
}

__global__ void place_kernel(const int2* __restrict__ top2, const int* __restrict__ base,
                             int* __restrict__ buf, int* __restrict__ inv) {
    const int chunk = blockIdx.x;
    const int tid = threadIdx.x;           // 1024
    const int wid = tid >> 6, lane = tid & 63;
    const int t = chunk * 1024 + tid;
    __shared__ int wpre[NEXP][16];
    const int2 tp = top2[t];
    int lpre[NEXP]; bool mm[NEXP];
#pragma unroll
    for (int e = 0; e < NEXP; e++) {
        mm[e] = (tp.x == e) || (tp.y == e);
        unsigned long long bal = __ballot(mm[e]);
        lpre[e] = __popcll(bal & ((1ull << lane) - 1ull));
        if (lane == 0) wpre[e][wid] = __popcll(bal);
    }
    __syncthreads();
    if (tid < NEXP) {
        int a = 0;
        for (int w = 0; w < 16; w++) { int v = wpre[tid][w]; wpre[tid][w] = a; a += v; }
    }
    __syncthreads();
#pragma unroll
    for (int e = 0; e < NEXP; e++) {
        if (mm[e]) {
            const int pos = base[chunk * NEXP + e] + wpre[e][wid] + lpre[e];
            const int slot = (tp.x == e) ? 0 : 1;
            if (pos < CAP) {
                const int row = e * CAP + pos;
                buf[row] = t;
                inv[t * 2 + slot] = row;
            } else {
                inv[t * 2 + slot] = -1;
            }
        }
    }
}

__global__ void pad_kernel(const int* __restrict__ usage, int* __restrict__ buf) {
    const int e = blockIdx.x;
    const int u = usage[e];
    for (int p = u + threadIdx.x; p < CAP; p += blockDim.x) buf[e * CAP + p] = NTOK;
}

// =====================================================================
// Gather: Xg[row][d] = bf16(x[buf[row]][d])  (zero row for pad)
// =====================================================================
__global__ void gather_kernel(const float* __restrict__ x, const int* __restrict__ buf,
                              bf16_t* __restrict__ Xg) {
    const int row = blockIdx.x;
    const int t = buf[row];
    const int tid = threadIdx.x;   // 128, 8 elems each
    bf16x8 v;
    if (t >= 0 && t < NTOK) {
        const float* xr = x + (size_t)t * EMB_D + tid * 8;
        const float4 a = *(const float4*)(xr);
        const float4 b = *(const float4*)(xr + 4);
        v[0] = (bf16_t)a.x; v[1] = (bf16_t)a.y; v[2] = (bf16_t)a.z; v[3] = (bf16_t)a.w;
        v[4] = (bf16_t)b.x; v[5] = (bf16_t)b.y; v[6] = (bf16_t)b.z; v[7] = (bf16_t)b.w;
    } else {
#pragma unroll
        for (int i = 0; i < 8; i++) v[i] = (bf16_t)0.f;
    }
    *(bf16x8*)(Xg + (size_t)row * EMB_D + tid * 8) = v;
}

// =====================================================================
// Transpose + convert: in[e][R][C] fp32 -> out[e][C][R] bf16
// =====================================================================
__global__ void transpose_conv_kernel(const float* __restrict__ in, bf16_t* __restrict__ out,
                                      int R, int C) {
    __shared__ bf16_t tile[64][72];
    const int e = blockIdx.z;
    const int c0 = blockIdx.x * 64, r0 = blockIdx.y * 64;
    const float*  ip = in  + (size_t)e * R * C;
    bf16_t*       op = out + (size_t)e * R * C;
    const int tid = threadIdx.x;   // 256
    const int tr = tid >> 4;
    const int tc = (tid & 15) * 4;
#pragma unroll
    for (int rr = 0; rr < 64; rr += 16) {
        const float4 v = *(const float4*)(ip + (size_t)(r0 + tr + rr) * C + (c0 + tc));
        tile[tr + rr][tc + 0] = (bf16_t)v.x;
        tile[tr + rr][tc + 1] = (bf16_t)v.y;
        tile[tr + rr][tc + 2] = (bf16_t)v.z;
        tile[tr + rr][tc + 3] = (bf16_t)v.w;
    }
    __syncthreads();
    const int oc = tid >> 2;
    const int og = (tid & 3) * 16;
    bf16x8 v0, v1;
#pragma unroll
    for (int i = 0; i < 8; i++) v0[i] = tile[og + i][oc];
#pragma unroll
    for (int i = 0; i < 8; i++) v1[i] = tile[og + 8 + i][oc];
    *(bf16x8*)(op + (size_t)(c0 + oc) * R + r0 + og)     = v0;
    *(bf16x8*)(op + (size_t)(c0 + oc) * R + r0 + og + 8) = v1;
}

// =====================================================================
// 256x256 2-phase MFMA GEMM, 3-bit XOR swizzle (verified 0 bank conflicts)
//   BM=BN=256, BK=64, 512 threads = 8 waves (2 M x 4 N), per-wave 128x64 out.
//   LDS: 2 buffers x (A 32KB + B 32KB) = 128 KB (dynamic).
//   Fragment addr: byte = row*128 + (((ks*4+quad) ^ (row&7)) << 4)
//   global_load_lds dest LINEAR, source 16B-slot pre-permuted by the same
//   involution (both-sides rule).
//   Per tile: PH-A{read a_lo+b_all; stage A(t+1); lgkm; 32 MFMA; barrier}
//             PH-B{read a_hi;       stage B(t+2); lgkm; 32 MFMA; vmcnt(4); barrier}
//   2 barriers/tile. vmcnt(4): 12 gloads outstanding -> keep B(t+2)'s 4 in
//   flight, A(t+1)+B(t+1) proven resident. Tail stages use wrapped src tiles
//   (keeps vmcnt arithmetic exact); drained by vmcnt(0)+barrier before the
//   epilogue reuses LDS.
// =====================================================================
#define BUF_BYTES 65536
#define LDS_TOTAL 131072

__device__ __forceinline__ const bf16x8* fragp(const char* base, int row, int ks, int quad) {
    return (const bf16x8*)(base + row * 128 + ((((ks << 2) + quad) ^ (row & 7)) << 4));
}

// stage one full 32KB panel (256 rows x 64 K) = 4 gload instrs / thread
__device__ __forceinline__ void stage_panel(const bf16_t* __restrict__ P, int K,
                                            char* lds0, int dstpar, int isB,
                                            int srct, int tid) {
    char* dst = lds0 + dstpar * BUF_BYTES + (isB ? 32768 : 0) + tid * 16;
    const int row0 = tid >> 3;                    // 0..63
    const int sq   = (tid & 7) ^ (row0 & 7);      // pre-swizzled 16B slot
    const bf16_t* src = P + (size_t)row0 * K + (size_t)srct * 64 + sq * 8;
    gload_lds16(src, dst);
    gload_lds16(src + (size_t)64 * K,  dst + 8192);
    gload_lds16(src + (size_t)128 * K, dst + 16384);
    gload_lds16(src + (size_t)192 * K, dst + 24576);
}

template <int NT>
__device__ __forceinline__ void mainloop256(const bf16_t* __restrict__ Ap,
                                            const bf16_t* __restrict__ Bp,
                                            char* lds0, f32x4 (&acc)[8][4]) {
    const int K = NT * 64;
    const int tid = threadIdx.x;
    const int lane = tid & 63, wid = tid >> 6;
    const int wm = wid >> 2, wn = wid & 3;
    const int quad = lane >> 4, l16 = lane & 15;

    // prologue: B(0), A(0), B(1)  (12 gloads); vmcnt(4) -> tile0 resident
    stage_panel(Bp, K, lds0, 0, 1, 0, tid);
    stage_panel(Ap, K, lds0, 0, 0, 0, tid);
    stage_panel(Bp, K, lds0, 1, 1, (NT > 1 ? 1 : 0), tid);
    asm volatile("s_waitcnt vmcnt(4)" ::: "memory");
    __builtin_amdgcn_s_barrier();

    bf16x8 aa[8], bb[8];
    for (int t = 0; t < NT; ++t) {
        const char* bufA = lds0 + (t & 1) * BUF_BYTES;
        const char* bufB = bufA + 32768;

        // ---- PH-A: read a_lo(8)+b_all(8); stage A(t+1); 32 MFMA (m-lo)
#pragma unroll
        for (int mf = 0; mf < 4; ++mf)
#pragma unroll
            for (int ks = 0; ks < 2; ++ks)
                aa[mf * 2 + ks] = *fragp(bufA, wm * 128 + mf * 16 + l16, ks, quad);
#pragma unroll
        for (int nf = 0; nf < 4; ++nf)
#pragma unroll
            for (int ks = 0; ks < 2; ++ks)
                bb[nf * 2 + ks] = *fragp(bufB, wn * 64 + nf * 16 + l16, ks, quad);
        stage_panel(Ap, K, lds0, (t + 1) & 1, 0, (t + 1 < NT ? t + 1 : 0), tid);
        asm volatile("s_waitcnt lgkmcnt(0)" ::: "memory");
        __builtin_amdgcn_sched_barrier(0);           // rule 18: pin MFMA below the wait
        __builtin_amdgcn_s_setprio(1);
#pragma unroll
        for (int mf = 0; mf < 4; ++mf)
#pragma unroll
            for (int nf = 0; nf < 4; ++nf)
#pragma unroll
                for (int ks = 0; ks < 2; ++ks)
                    acc[mf][nf] = __builtin_amdgcn_mfma_f32_16x16x32_bf16(
                        aa[mf * 2 + ks], bb[nf * 2 + ks], acc[mf][nf], 0, 0, 0);
        __builtin_amdgcn_s_setprio(0);
        __builtin_amdgcn_s_barrier();                // gates PH-B's B(t+2) overwrite

        // ---- PH-B: read a_hi(8); stage B(t+2); 32 MFMA (m-hi); counted vmcnt
#pragma unroll
        for (int mf = 0; mf < 4; ++mf)
#pragma unroll
            for (int ks = 0; ks < 2; ++ks)
                aa[mf * 2 + ks] = *fragp(bufA, wm * 128 + (mf + 4) * 16 + l16, ks, quad);
        stage_panel(Bp, K, lds0, t & 1, 1, (t + 2 < NT ? t + 2 : t + 2 - NT), tid);
        asm volatile("s_waitcnt lgkmcnt(0)" ::: "memory");
        __builtin_amdgcn_sched_barrier(0);
        __builtin_amdgcn_s_setprio(1);
#pragma unroll
        for (int mf = 0; mf < 4; ++mf)
#pragma unroll
            for (int nf = 0; nf < 4; ++nf)
#pragma unroll
                for (int ks = 0; ks < 2; ++ks)
                    acc[mf + 4][nf] = __builtin_amdgcn_mfma_f32_16x16x32_bf16(
                        aa[mf * 2 + ks], bb[nf * 2 + ks], acc[mf + 4][nf], 0, 0, 0);
        __builtin_amdgcn_s_setprio(0);
        asm volatile("s_waitcnt vmcnt(4)" ::: "memory");  // tile t+1 resident
        __builtin_amdgcn_s_barrier();
    }
    // drain wrapped tail stages before epilogue reuses LDS
    asm volatile("s_waitcnt vmcnt(0)" ::: "memory");
    __builtin_amdgcn_s_barrier();
}

// epilogue store: acc -> per-wave 8KB LDS (XOR-swizzled, 16B aligned) ->
// bf16x8 reads -> 128B-contiguous global stores. APPLY = 0: raw, 1: bias+gelu.
template <int APPLY>
__device__ __forceinline__ void epilogue_store(const f32x4 (&acc)[8][4], char* lds0,
                                               const float* __restrict__ bias4,
                                               bf16_t* __restrict__ Out, int ldo,
                                               int bm, int bn) {
    const int tid = threadIdx.x;
    const int lane = tid & 63, wid = tid >> 6;
    const int wm = wid >> 2, wn = wid & 3;
    const int quad = lane >> 4, l16 = lane & 15;
    const int l8 = lane & 7, g8 = lane >> 3;
    char* eb = lds0 + wid * 8192;                 // per-wave 64 rows x 128B
    const int rslot = (l8 ^ g8) << 4;             // read swizzle (const per lane)
#pragma unroll
    for (int h = 0; h < 2; ++h) {
#pragma unroll
        for (int mfh = 0; mfh < 4; ++mfh) {
#pragma unroll
            for (int r = 0; r < 4; ++r) {
                const int lrow = mfh * 16 + quad * 4 + r;
#pragma unroll
                for (int nf = 0; nf < 4; ++nf) {
                    float v = acc[h * 4 + mfh][nf][r];
                    if (APPLY) {
                        v += bias4[nf];
                        v = 0.5f * v * (1.f + erff(v * 0.7071067811865475f));
                    }
                    const int lcol = nf * 16 + l16;
                    const int byte = lrow * 128 +
                        (((lcol >> 3) ^ (lrow & 7)) << 4) + ((lcol & 7) << 1);
                    *(bf16_t*)(eb + byte) = (bf16_t)v;
                }
            }
        }
        asm volatile("s_waitcnt lgkmcnt(0)" ::: "memory");
        __builtin_amdgcn_sched_barrier(0);
#pragma unroll
        for (int i = 0; i < 8; ++i) {
            const int rr = i * 8 + g8;
            const bf16x8 v = *(const bf16x8*)(eb + rr * 128 + rslot);
            const int grow = bm * 256 + wm * 128 + h * 64 + rr;
            const int gcol = bn * 256 + wn * 64 + l8 * 8;
            *(bf16x8*)(Out + (size_t)grow * ldo + gcol) = v;
        }
        asm volatile("s_waitcnt lgkmcnt(0)" ::: "memory");  // reads done before next h
        __builtin_amdgcn_sched_barrier(0);
    }
}

// GEMM1: H = gelu_exact(Xg @ w1t^T + b1), bf16 out.
__global__ __launch_bounds__(512, 2) void gemm1_kernel(const bf16_t* __restrict__ Xg,
                                                       const bf16_t* __restrict__ w1t,
                                                       const float* __restrict__ b1,
                                                       bf16_t* __restrict__ H) {
    extern __shared__ char lds0[];
    const int bn = blockIdx.x, bm = blockIdx.y;
    const int e = bm / (CAP / 256);
    const bf16_t* Ap = Xg + (size_t)bm * 256 * EMB_D;
    const bf16_t* Bp = w1t + ((size_t)e * HID_H + bn * 256) * EMB_D;
    f32x4 acc[8][4];
    const f32x4 z4 = {0.f, 0.f, 0.f, 0.f};
#pragma unroll
    for (int i = 0; i < 8; i++)
#pragma unroll
        for (int j = 0; j < 4; j++) acc[i][j] = z4;

    mainloop256<EMB_D / 64>(Ap, Bp, lds0, acc);

    const int lane = threadIdx.x & 63, wid = threadIdx.x >> 6;
    const int wn = wid & 3, l16 = lane & 15;
    float bias4[4];
#pragma unroll
    for (int nf = 0; nf < 4; ++nf)
        bias4[nf] = b1[e * HID_H + bn * 256 + wn * 64 + nf * 16 + l16];
    epilogue_store<1>(acc, lds0, bias4, H, HID_H, bm, bn);
}

// GEMM2: Yg = H @ w2t^T (bf16, dense; bias added in combine).
__global__ __launch_bounds__(512, 2) void gemm2_kernel(const bf16_t* __restrict__ H,
                                                       const bf16_t* __restrict__ w2t,
                                                       bf16_t* __restrict__ Yg) {
    extern __shared__ char lds0[];
    const int bn = blockIdx.x, bm = blockIdx.y;
    const int e = bm / (CAP / 256);
    const bf16_t* Ap = H + (size_t)bm * 256 * HID_H;
    const bf16_t* Bp = w2t + ((size_t)e * EMB_D + bn * 256) * HID_H;
    f32x4 acc[8][4];
    const f32x4 z4 = {0.f, 0.f, 0.f, 0.f};
#pragma unroll
    for (int i = 0; i < 8; i++)
#pragma unroll
        for (int j = 0; j < 4; j++) acc[i][j] = z4;

    mainloop256<HID_H / 64>(Ap, Bp, lds0, acc);

    epilogue_store<0>(acc, lds0, nullptr, Yg, EMB_D, bm, bn);
}

// =====================================================================
// Combine: out[t] = sum over kept slots (Yg[row] + b2[expert]) ; 0 if dropped
// =====================================================================
__global__ void combine_kernel(const bf16_t* __restrict__ Yg, const float* __restrict__ b2,
                               const int* __restrict__ inv, float* __restrict__ out) {
    const int t = blockIdx.x;
    const int tid = threadIdx.x;   // 128, 8 floats each
    const int d = tid * 8;
    const int r0 = inv[t * 2], r1 = inv[t * 2 + 1];
    float acc[8];
#pragma unroll
    for (int i = 0; i < 8; i++) acc[i] = 0.f;
    if (r0 >= 0) {
        const int e = r0 / CAP;
        const bf16x8 v = *(const bf16x8*)(Yg + (size_t)r0 * EMB_D + d);
        const float* bp = b2 + e * EMB_D + d;
#pragma unroll
        for (int i = 0; i < 8; i++) acc[i] += (float)v[i] + bp[i];
    }
    if (r1 >= 0) {
        const int e = r1 / CAP;
        const bf16x8 v = *(const bf16x8*)(Yg + (size_t)r1 * EMB_D + d);
        const float* bp = b2 + e * EMB_D + d;
#pragma unroll
        for (int i = 0; i < 8; i++) acc[i] += (float)v[i] + bp[i];
    }
    float4 o0 = {acc[0], acc[1], acc[2], acc[3]};
    float4 o1 = {acc[4], acc[5], acc[6], acc[7]};
    *(float4*)(out + (size_t)t * EMB_D + d)     = o0;
    *(float4*)(out + (size_t)t * EMB_D + d + 4) = o1;
}

// =====================================================================
// Finalize: loss = E*sum(load^2) + 0.001*mean(logits^2); usage floats.
// =====================================================================
__global__ void finalize_kernel(const int* __restrict__ usage, const float* __restrict__ zsum,
                                float* __restrict__ out) {
    if (threadIdx.x == 0) {
        float u[NEXP], s = 0.f;
        for (int e = 0; e < NEXP; e++) { u[e] = (float)usage[e]; s += u[e]; }
        const float inv = 1.f / (s + 1e-6f);
        float bal = 0.f;
        for (int e = 0; e < NEXP; e++) { const float l = u[e] * inv; bal += l * l; }
        bal *= (float)NEXP;
        const float z = 0.001f * zsum[0] / (float)((size_t)NTOK * NEXP);
        out[(size_t)NTOK * EMB_D] = bal + z;
        for (int e = 0; e < NEXP; e++) out[(size_t)NTOK * EMB_D + 1 + e] = u[e];
    }
}

extern "C" void kernel_launch(void* const* d_in, const int* in_sizes, int n_in,
                              void* d_out, int out_size, void* d_ws, size_t ws_size,
                              hipStream_t stream) {
    (void)in_sizes; (void)n_in; (void)out_size;
    const float* x  = (const float*)d_in[0];
    const float* wr = (const float*)d_in[1];
    const float* br = (const float*)d_in[2];
    const float* w1 = (const float*)d_in[3];
    const float* b1 = (const float*)d_in[4];
    const float* w2 = (const float*)d_in[5];
    const float* b2 = (const float*)d_in[6];
    float* out = (float*)d_out;

    uint8_t* ws = (uint8_t*)d_ws;
    size_t off = 0;
    auto carve = [&](size_t bytes) -> void* {
        off = (off + 255) & ~(size_t)255;
        void* p = ws + off;
        off += bytes;
        return p;
    };
    float*  zsum  = (float*)carve(sizeof(float));
    int*    usage = (int*)carve(NEXP * sizeof(int));
    int*    counts = (int*)carve((size_t)NCHUNK * NEXP * sizeof(int));
    int*    base   = (int*)carve((size_t)NCHUNK * NEXP * sizeof(int));
    int2*   top2 = (int2*)carve((size_t)NTOK * sizeof(int2));
    int*    buf  = (int*)carve((size_t)MROWS * sizeof(int));
    int*    inv  = (int*)carve((size_t)NTOK * 2 * sizeof(int));
    bf16_t* Xg   = (bf16_t*)carve((size_t)MROWS * EMB_D * sizeof(bf16_t));
    bf16_t* w1t  = (bf16_t*)carve((size_t)NEXP * HID_H * EMB_D * sizeof(bf16_t));
    bf16_t* w2t  = (bf16_t*)carve((size_t)NEXP * EMB_D * HID_H * sizeof(bf16_t));
    bf16_t* H    = (bf16_t*)carve((size_t)MROWS * HID_H * sizeof(bf16_t));
    bf16_t* Yg   = Xg;   // Xg is dead after gemm1 -> reuse for gemm2 output
    if (off > ws_size) return;   // workspace too small: fail loudly

    static bool attr_set = false;
    if (!attr_set) {
        hipFuncSetAttribute(reinterpret_cast<const void*>(&gemm1_kernel),
                            hipFuncAttributeMaxDynamicSharedMemorySize, LDS_TOTAL);
        hipFuncSetAttribute(reinterpret_cast<const void*>(&gemm2_kernel),
                            hipFuncAttributeMaxDynamicSharedMemorySize, LDS_TOTAL);
        attr_set = true;
    }

    hipMemsetAsync(zsum, 0, sizeof(float), stream);

    router_kernel<<<NTOK / 4, 256, 0, stream>>>(x, wr, br, top2, zsum);
    count_kernel<<<NCHUNK, 1024, 0, stream>>>(top2, counts);
    prefix_kernel<<<1, 64, 0, stream>>>(counts, base, usage);
    place_kernel<<<NCHUNK, 1024, 0, stream>>>(top2, base, buf, inv);
    pad_kernel<<<NEXP, 256, 0, stream>>>(usage, buf);
    gather_kernel<<<MROWS, 128, 0, stream>>>(x, buf, Xg);
    transpose_conv_kernel<<<dim3(HID_H / 64, EMB_D / 64, NEXP), 256, 0, stream>>>(w1, w1t, EMB_D, HID_H);
    transpose_conv_kernel<<<dim3(EMB_D / 64, HID_H / 64, NEXP), 256, 0, stream>>>(w2, w2t, HID_H, EMB_D);
    gemm1_kernel<<<dim3(HID_H / 256, MROWS / 256), 512, LDS_TOTAL, stream>>>(Xg, w1t, b1, H);
    gemm2_kernel<<<dim3(EMB_D / 256, MROWS / 256), 512, LDS_TOTAL, stream>>>(H, w2t, Yg);
    combine_kernel<<<NTOK, 128, 0, stream>>>(Yg, b2, inv, out);
    finalize_kernel<<<1, 64, 0, stream>>>(usage, zsum, out);
}